// Round 1
// baseline (914.151 us; speedup 1.0000x reference)
//
#include <hip/hip_runtime.h>

// Problem constants (fixed by reference)
#define IN_DIM 256
#define HC     128   // H*C
#define NHEAD  4
#define CDIM   32
#define NEG    0.2f

// ---------------- W transpose: Wt[c][k] = W[k][c] ----------------
__global__ void transpose_w_kernel(const float* __restrict__ W, float* __restrict__ Wt) {
    int idx = blockIdx.x * 256 + threadIdx.x;   // 256*128 = 32768
    if (idx >= IN_DIM * HC) return;
    int k = idx >> 7;          // 0..255
    int c = idx & 127;         // 0..127
    Wt[c * IN_DIM + k] = W[idx];
}

// ---------------- GEMM: h = x @ W  (fp32) ----------------
// block 256 threads: col = tid&127, rhalf = tid>>7, 8 rows each; 16 rows/block
__global__ __launch_bounds__(256) void gemm_kernel(const float* __restrict__ x,
                                                   const float* __restrict__ Wt,
                                                   float* __restrict__ h, int n) {
    __shared__ float xs[16][IN_DIM];   // 16 KB
    const int tid  = threadIdx.x;
    const int row0 = blockIdx.x * 16;

    // stage 16 rows of x (4096 floats = 1024 float4)
    const float4* xsrc = reinterpret_cast<const float4*>(x + (size_t)row0 * IN_DIM);
    float4* xdst = reinterpret_cast<float4*>(&xs[0][0]);
#pragma unroll
    for (int i = 0; i < 4; ++i) xdst[tid + i * 256] = xsrc[tid + i * 256];
    __syncthreads();

    const int col = tid & 127;
    const int rh  = tid >> 7;   // 0 or 1
    float acc[8];
#pragma unroll
    for (int r = 0; r < 8; ++r) acc[r] = 0.f;

    const float4* wt4 = reinterpret_cast<const float4*>(Wt + col * IN_DIM);
    for (int k4 = 0; k4 < IN_DIM / 4; ++k4) {
        float4 wv = wt4[k4];
#pragma unroll
        for (int r = 0; r < 8; ++r) {
            float4 xv = *reinterpret_cast<const float4*>(&xs[rh * 8 + r][k4 * 4]);
            acc[r] = fmaf(xv.x, wv.x, acc[r]);
            acc[r] = fmaf(xv.y, wv.y, acc[r]);
            acc[r] = fmaf(xv.z, wv.z, acc[r]);
            acc[r] = fmaf(xv.w, wv.w, acc[r]);
        }
    }
#pragma unroll
    for (int r = 0; r < 8; ++r) {
        int row = row0 + rh * 8 + r;
        if (row < n) h[(size_t)row * HC + col] = acc[r];
    }
}

// ---------------- per-node attention logits ----------------
__global__ void alpha_kernel(const float* __restrict__ h,
                             const float* __restrict__ a_src,
                             const float* __restrict__ a_dst,
                             float* __restrict__ alpha_s,
                             float* __restrict__ alpha_d, int n) {
    int gid = blockIdx.x * 256 + threadIdx.x;    // one per (node, head)
    if (gid >= n * NHEAD) return;
    int head = gid & 3;
    int node = gid >> 2;
    const float4* h4  = reinterpret_cast<const float4*>(h + (size_t)node * HC + head * CDIM);
    const float4* as4 = reinterpret_cast<const float4*>(a_src + head * CDIM);
    const float4* ad4 = reinterpret_cast<const float4*>(a_dst + head * CDIM);
    float ss = 0.f, sd = 0.f;
#pragma unroll
    for (int i = 0; i < 8; ++i) {
        float4 hv = h4[i], av = as4[i], dv = ad4[i];
        ss += hv.x * av.x + hv.y * av.y + hv.z * av.z + hv.w * av.w;
        sd += hv.x * dv.x + hv.y * dv.y + hv.z * dv.z + hv.w * dv.w;
    }
    alpha_s[gid] = ss;
    alpha_d[gid] = sd;
}

// ---------------- edge pass: p = exp(leakyrelu(as+ad)); s_sum[dst] += p ----------------
__global__ void edge_kernel(const int* __restrict__ ei,
                            const float* __restrict__ alpha_s,
                            const float* __restrict__ alpha_d,
                            float* __restrict__ p, float* __restrict__ s_sum,
                            int E, int n) {
    int i = blockIdx.x * 256 + threadIdx.x;
    int tot = E + n;
    if (i >= tot) return;
    int src, dst;
    if (i < E) { src = ei[i]; dst = ei[E + i]; }
    else       { src = dst = i - E; }
    float4 as = *reinterpret_cast<const float4*>(alpha_s + (size_t)src * 4);
    float4 ad = *reinterpret_cast<const float4*>(alpha_d + (size_t)dst * 4);
    float e0 = as.x + ad.x, e1 = as.y + ad.y, e2 = as.z + ad.z, e3 = as.w + ad.w;
    e0 = e0 > 0.f ? e0 : NEG * e0;
    e1 = e1 > 0.f ? e1 : NEG * e1;
    e2 = e2 > 0.f ? e2 : NEG * e2;
    e3 = e3 > 0.f ? e3 : NEG * e3;
    float p0 = __expf(e0), p1 = __expf(e1), p2 = __expf(e2), p3 = __expf(e3);
    *reinterpret_cast<float4*>(p + (size_t)i * 4) = make_float4(p0, p1, p2, p3);
    atomicAdd(&s_sum[dst * 4 + 0], p0);
    atomicAdd(&s_sum[dst * 4 + 1], p1);
    atomicAdd(&s_sum[dst * 4 + 2], p2);
    atomicAdd(&s_sum[dst * 4 + 3], p3);
}

// ---------------- scatter: out[dst] += (p/s) * h[src]  (one wave per edge) ----------------
__global__ __launch_bounds__(256) void scatter_kernel(const int* __restrict__ ei,
                                                      const float* __restrict__ p,
                                                      const float* __restrict__ s_sum,
                                                      const float* __restrict__ h,
                                                      float* __restrict__ out,
                                                      int E, int n) {
    int lane = threadIdx.x & 63;
    int edge = blockIdx.x * 4 + (threadIdx.x >> 6);
    if (edge >= E + n) return;
    int src, dst;
    if (edge < E) { src = ei[edge]; dst = ei[E + edge]; }
    else          { src = dst = edge - E; }
    float4 pv = *reinterpret_cast<const float4*>(p + (size_t)edge * 4);
    float4 sv = *reinterpret_cast<const float4*>(s_sum + (size_t)dst * 4);
    float w0 = pv.x / sv.x, w1 = pv.y / sv.y, w2 = pv.z / sv.z, w3 = pv.w / sv.w;
    const float* hrow = h + (size_t)src * HC;
    float hv0 = hrow[lane];
    float hv1 = hrow[lane + 64];
    float wa = (lane < 32) ? w0 : w1;   // channels 0..63 -> heads 0,1
    float wb = (lane < 32) ? w2 : w3;   // channels 64..127 -> heads 2,3
    float* orow = out + (size_t)dst * HC;
    atomicAdd(&orow[lane],      wa * hv0);
    atomicAdd(&orow[lane + 64], wb * hv1);
}

// ---------------- finalize: out = tanh(out + bias) ----------------
__global__ void finalize_kernel(float* __restrict__ out, const float* __restrict__ bias,
                                int total4) {
    int i = blockIdx.x * 256 + threadIdx.x;
    if (i >= total4) return;
    float4 v = reinterpret_cast<float4*>(out)[i];
    float4 b = reinterpret_cast<const float4*>(bias)[i & 31];  // 32 float4 per row
    v.x = tanhf(v.x + b.x);
    v.y = tanhf(v.y + b.y);
    v.z = tanhf(v.z + b.z);
    v.w = tanhf(v.w + b.w);
    reinterpret_cast<float4*>(out)[i] = v;
}

extern "C" void kernel_launch(void* const* d_in, const int* in_sizes, int n_in,
                              void* d_out, int out_size, void* d_ws, size_t ws_size,
                              hipStream_t stream) {
    const float* x     = (const float*)d_in[0];
    const float* W     = (const float*)d_in[1];
    const float* a_src = (const float*)d_in[2];
    const float* a_dst = (const float*)d_in[3];
    const float* bias  = (const float*)d_in[4];
    const int*   ei    = (const int*)d_in[5];

    const int n = in_sizes[0] / IN_DIM;        // 100000
    const int E = in_sizes[5] / 2;             // 1000000
    const int tot = E + n;

    float* ws = (float*)d_ws;
    size_t off = 0;
    float* Wt      = ws + off; off += (size_t)IN_DIM * HC;     // 32768
    float* h       = ws + off; off += (size_t)n * HC;          // 12.8M
    float* alpha_s = ws + off; off += (size_t)n * NHEAD;
    float* alpha_d = ws + off; off += (size_t)n * NHEAD;
    float* s_sum   = ws + off; off += (size_t)n * NHEAD;
    float* p       = ws + off; off += (size_t)tot * NHEAD;

    float* out = (float*)d_out;

    // zero accumulators (harness poisons buffers; we accumulate)
    hipMemsetAsync(s_sum, 0, (size_t)n * NHEAD * sizeof(float), stream);
    hipMemsetAsync(out, 0, (size_t)n * HC * sizeof(float), stream);

    transpose_w_kernel<<<(IN_DIM * HC + 255) / 256, 256, 0, stream>>>(W, Wt);
    gemm_kernel<<<(n + 15) / 16, 256, 0, stream>>>(x, Wt, h, n);
    alpha_kernel<<<(n * NHEAD + 255) / 256, 256, 0, stream>>>(h, a_src, a_dst, alpha_s, alpha_d, n);
    edge_kernel<<<(tot + 255) / 256, 256, 0, stream>>>(ei, alpha_s, alpha_d, p, s_sum, E, n);
    scatter_kernel<<<(tot + 3) / 4, 256, 0, stream>>>(ei, p, s_sum, h, out, E, n);
    finalize_kernel<<<(n * HC / 4 + 255) / 256, 256, 0, stream>>>(out, bias, n * HC / 4);
}

// Round 2
// 481.511 us; speedup vs baseline: 1.8985x; 1.8985x over previous
//
#include <hip/hip_runtime.h>

#define IN_DIM 256
#define HC     128   // H*C
#define NHEAD  4
#define CDIM   32
#define NEG    0.2f

// ---------------- W transpose: Wt[c][k] = W[k][c] ----------------
__global__ void transpose_w_kernel(const float* __restrict__ W, float* __restrict__ Wt) {
    int idx = blockIdx.x * 256 + threadIdx.x;   // 256*128 = 32768
    if (idx >= IN_DIM * HC) return;
    int k = idx >> 7;
    int c = idx & 127;
    Wt[c * IN_DIM + k] = W[idx];
}

// ---------------- GEMM: h = x @ W  (fp32) ----------------
__global__ __launch_bounds__(256) void gemm_kernel(const float* __restrict__ x,
                                                   const float* __restrict__ Wt,
                                                   float* __restrict__ h, int n) {
    __shared__ float xs[16][IN_DIM];   // 16 KB
    const int tid  = threadIdx.x;
    const int row0 = blockIdx.x * 16;

    const float4* xsrc = reinterpret_cast<const float4*>(x + (size_t)row0 * IN_DIM);
    float4* xdst = reinterpret_cast<float4*>(&xs[0][0]);
#pragma unroll
    for (int i = 0; i < 4; ++i) xdst[tid + i * 256] = xsrc[tid + i * 256];
    __syncthreads();

    const int col = tid & 127;
    const int rh  = tid >> 7;
    float acc[8];
#pragma unroll
    for (int r = 0; r < 8; ++r) acc[r] = 0.f;

    const float4* wt4 = reinterpret_cast<const float4*>(Wt + col * IN_DIM);
    for (int k4 = 0; k4 < IN_DIM / 4; ++k4) {
        float4 wv = wt4[k4];
#pragma unroll
        for (int r = 0; r < 8; ++r) {
            float4 xv = *reinterpret_cast<const float4*>(&xs[rh * 8 + r][k4 * 4]);
            acc[r] = fmaf(xv.x, wv.x, acc[r]);
            acc[r] = fmaf(xv.y, wv.y, acc[r]);
            acc[r] = fmaf(xv.z, wv.z, acc[r]);
            acc[r] = fmaf(xv.w, wv.w, acc[r]);
        }
    }
#pragma unroll
    for (int r = 0; r < 8; ++r) {
        int row = row0 + rh * 8 + r;
        if (row < n) h[(size_t)row * HC + col] = acc[r];
    }
}

// ---------------- per-node attention logits ----------------
__global__ void alpha_kernel(const float* __restrict__ h,
                             const float* __restrict__ a_src,
                             const float* __restrict__ a_dst,
                             float* __restrict__ alpha_s,
                             float* __restrict__ alpha_d, int n) {
    int gid = blockIdx.x * 256 + threadIdx.x;    // one per (node, head)
    if (gid >= n * NHEAD) return;
    int head = gid & 3;
    int node = gid >> 2;
    const float4* h4  = reinterpret_cast<const float4*>(h + (size_t)node * HC + head * CDIM);
    const float4* as4 = reinterpret_cast<const float4*>(a_src + head * CDIM);
    const float4* ad4 = reinterpret_cast<const float4*>(a_dst + head * CDIM);
    float ss = 0.f, sd = 0.f;
#pragma unroll
    for (int i = 0; i < 8; ++i) {
        float4 hv = h4[i], av = as4[i], dv = ad4[i];
        ss += hv.x * av.x + hv.y * av.y + hv.z * av.z + hv.w * av.w;
        sd += hv.x * dv.x + hv.y * dv.y + hv.z * dv.z + hv.w * dv.w;
    }
    alpha_s[gid] = ss;
    alpha_d[gid] = sd;
}

// ---------------- CSR build ----------------
__global__ void init_deg_kernel(int* __restrict__ deg, int n) {
    int i = blockIdx.x * 256 + threadIdx.x;
    if (i < n) deg[i] = 1;   // self-loop
}

__global__ void count_deg_kernel(const int* __restrict__ ei, int* __restrict__ deg, int E) {
    int i = blockIdx.x * 256 + threadIdx.x;
    if (i < E) atomicAdd(&deg[ei[E + i]], 1);
}

// scan1: 1024 elems/block (256 thr x 4), exclusive within block, block total out
__global__ __launch_bounds__(256) void scan1_kernel(const int* __restrict__ deg,
                                                    int* __restrict__ row_start,
                                                    int* __restrict__ blk_sums, int n) {
    __shared__ int warp_sums[4];
    int t = threadIdx.x;
    int base = blockIdx.x * 1024 + t * 4;
    int v[4];
#pragma unroll
    for (int i = 0; i < 4; ++i) v[i] = (base + i < n) ? deg[base + i] : 0;
    int tsum = v[0] + v[1] + v[2] + v[3];
    int lane = t & 63, w = t >> 6;
    int x = tsum;
    for (int off = 1; off < 64; off <<= 1) {
        int y = __shfl_up(x, off);
        if (lane >= off) x += y;
    }
    if (lane == 63) warp_sums[w] = x;
    __syncthreads();
    int wo = 0;
    for (int i = 0; i < w; ++i) wo += warp_sums[i];
    int run = wo + x - tsum;   // exclusive prefix for this thread
#pragma unroll
    for (int i = 0; i < 4; ++i) {
        if (base + i < n) row_start[base + i] = run;
        run += v[i];
    }
    if (t == 255) blk_sums[blockIdx.x] = wo + x;
}

// scan2: single block, exclusive scan of blk_sums (nb <= 256)
__global__ __launch_bounds__(256) void scan2_kernel(int* __restrict__ bs, int nb) {
    __shared__ int warp_sums[4];
    int t = threadIdx.x;
    int v = (t < nb) ? bs[t] : 0;
    int lane = t & 63, w = t >> 6;
    int x = v;
    for (int off = 1; off < 64; off <<= 1) {
        int y = __shfl_up(x, off);
        if (lane >= off) x += y;
    }
    if (lane == 63) warp_sums[w] = x;
    __syncthreads();
    int wo = 0;
    for (int i = 0; i < w; ++i) wo += warp_sums[i];
    if (t < nb) bs[t] = wo + x - v;
}

__global__ void scan3_kernel(int* __restrict__ row_start, const int* __restrict__ bs, int n) {
    int i = blockIdx.x * 256 + threadIdx.x;
    if (i < n) row_start[i] += bs[i >> 10];
}

__global__ void fill_kernel(const int* __restrict__ ei, const int* __restrict__ row_start,
                            int* __restrict__ cursor, int* __restrict__ csr_src,
                            int E, int n) {
    int i = blockIdx.x * 256 + threadIdx.x;
    if (i >= E + n) return;
    int src, dst;
    if (i < E) { src = ei[i]; dst = ei[E + i]; }
    else       { src = dst = i - E; }
    int pos = row_start[dst] + atomicAdd(&cursor[dst], 1);
    csr_src[pos] = src;
}

// ---------------- fused gather: softmax + weighted sum + bias + tanh ----------------
// one wave per dst node; lane owns channels {2*lane, 2*lane+1} (same head = lane>>4)
__global__ __launch_bounds__(256) void gather_kernel(const int* __restrict__ row_start,
                                                     const int* __restrict__ deg,
                                                     const int* __restrict__ csr_src,
                                                     const float* __restrict__ alpha_s,
                                                     const float* __restrict__ alpha_d,
                                                     const float* __restrict__ h,
                                                     const float* __restrict__ bias,
                                                     float* __restrict__ out, int n) {
    int lane = threadIdx.x & 63;
    int v = blockIdx.x * 4 + (threadIdx.x >> 6);
    if (v >= n) return;
    int start = row_start[v];
    int cnt = deg[v];

    float4 ad = *reinterpret_cast<const float4*>(alpha_d + (size_t)v * 4);

    // pass 1: softmax denominators (4 heads), edges strided over lanes
    float s0 = 0.f, s1 = 0.f, s2 = 0.f, s3 = 0.f;
    for (int j = lane; j < cnt; j += 64) {
        int src = csr_src[start + j];
        float4 as = *reinterpret_cast<const float4*>(alpha_s + (size_t)src * 4);
        float e0 = as.x + ad.x, e1 = as.y + ad.y, e2 = as.z + ad.z, e3 = as.w + ad.w;
        e0 = e0 > 0.f ? e0 : NEG * e0;
        e1 = e1 > 0.f ? e1 : NEG * e1;
        e2 = e2 > 0.f ? e2 : NEG * e2;
        e3 = e3 > 0.f ? e3 : NEG * e3;
        s0 += __expf(e0); s1 += __expf(e1); s2 += __expf(e2); s3 += __expf(e3);
    }
#pragma unroll
    for (int off = 32; off > 0; off >>= 1) {
        s0 += __shfl_xor(s0, off);
        s1 += __shfl_xor(s1, off);
        s2 += __shfl_xor(s2, off);
        s3 += __shfl_xor(s3, off);
    }
    float i0 = 1.f / (s0 + 1e-16f), i1 = 1.f / (s1 + 1e-16f);
    float i2 = 1.f / (s2 + 1e-16f), i3 = 1.f / (s3 + 1e-16f);

    // per-lane head selection (head = lane>>4)
    float invH = (lane < 32) ? ((lane < 16) ? i0 : i1) : ((lane < 48) ? i2 : i3);
    float adH  = (lane < 32) ? ((lane < 16) ? ad.x : ad.y) : ((lane < 48) ? ad.z : ad.w);
    int head = lane >> 4;

    // pass 2: weighted accumulate, lane's 2 channels
    float accx = 0.f, accy = 0.f;
    const float2* h2 = reinterpret_cast<const float2*>(h);
    for (int j = 0; j < cnt; ++j) {
        int src = csr_src[start + j];                 // wave-broadcast load
        float as = alpha_s[(size_t)src * 4 + head];   // 16-lane broadcast
        float e = as + adH;
        e = e > 0.f ? e : NEG * e;
        float w = __expf(e) * invH;
        float2 hv = h2[(size_t)src * 64 + lane];      // coalesced 512B/wave
        accx = fmaf(w, hv.x, accx);
        accy = fmaf(w, hv.y, accy);
    }
    float2 b = reinterpret_cast<const float2*>(bias)[lane];
    float2 o;
    o.x = tanhf(accx + b.x);
    o.y = tanhf(accy + b.y);
    reinterpret_cast<float2*>(out)[(size_t)v * 64 + lane] = o;
}

extern "C" void kernel_launch(void* const* d_in, const int* in_sizes, int n_in,
                              void* d_out, int out_size, void* d_ws, size_t ws_size,
                              hipStream_t stream) {
    const float* x     = (const float*)d_in[0];
    const float* W     = (const float*)d_in[1];
    const float* a_src = (const float*)d_in[2];
    const float* a_dst = (const float*)d_in[3];
    const float* bias  = (const float*)d_in[4];
    const int*   ei    = (const int*)d_in[5];

    const int n = in_sizes[0] / IN_DIM;        // 100000
    const int E = in_sizes[5] / 2;             // 1000000
    const int tot = E + n;

    float* ws = (float*)d_ws;
    size_t off = 0;
    float* Wt      = ws + off; off += (size_t)IN_DIM * HC;
    float* h       = ws + off; off += (size_t)n * HC;
    float* alpha_s = ws + off; off += (size_t)n * NHEAD;
    float* alpha_d = ws + off; off += (size_t)n * NHEAD;
    int* ibase     = (int*)(ws + off);
    int* deg       = ibase;                    // n
    int* row_start = ibase + n;                // n
    int* cursor    = ibase + 2 * (size_t)n;    // n
    int* blk_sums  = ibase + 3 * (size_t)n;    // <=256
    int* csr_src   = ibase + 3 * (size_t)n + 256;  // E+n

    float* out = (float*)d_out;

    const int nb = (n + 1023) / 1024;          // scan blocks

    hipMemsetAsync(cursor, 0, (size_t)n * sizeof(int), stream);

    transpose_w_kernel<<<(IN_DIM * HC + 255) / 256, 256, 0, stream>>>(W, Wt);
    gemm_kernel<<<(n + 15) / 16, 256, 0, stream>>>(x, Wt, h, n);
    alpha_kernel<<<(n * NHEAD + 255) / 256, 256, 0, stream>>>(h, a_src, a_dst, alpha_s, alpha_d, n);

    init_deg_kernel<<<(n + 255) / 256, 256, 0, stream>>>(deg, n);
    count_deg_kernel<<<(E + 255) / 256, 256, 0, stream>>>(ei, deg, E);
    scan1_kernel<<<nb, 256, 0, stream>>>(deg, row_start, blk_sums, n);
    scan2_kernel<<<1, 256, 0, stream>>>(blk_sums, nb);
    scan3_kernel<<<(n + 255) / 256, 256, 0, stream>>>(row_start, blk_sums, n);
    fill_kernel<<<(tot + 255) / 256, 256, 0, stream>>>(ei, row_start, cursor, csr_src, E, n);

    gather_kernel<<<(n + 3) / 4, 256, 0, stream>>>(row_start, deg, csr_src,
                                                   alpha_s, alpha_d, h, bias, out, n);
}

// Round 3
// 346.646 us; speedup vs baseline: 2.6371x; 1.3891x over previous
//
#include <hip/hip_runtime.h>

#define IN_DIM 256
#define HC     128   // H*C
#define NHEAD  4
#define CDIM   32
#define NEG    0.2f

typedef __attribute__((ext_vector_type(8))) short short8v;
typedef __attribute__((ext_vector_type(4))) float f32x4;

__device__ __forceinline__ unsigned short bf16_rn(float f) {
    unsigned u = __builtin_bit_cast(unsigned, f);
    return (unsigned short)((u + 0x7fffu + ((u >> 16) & 1u)) >> 16);
}
__device__ __forceinline__ float bf16_to_f32(unsigned short b) {
    unsigned u = ((unsigned)b) << 16;
    return __builtin_bit_cast(float, u);
}

// ---------------- pack W into MFMA fragment order, hi/lo bf16 ----------------
// frag index: ((s*8 + ct)*64 + lane)*8 + e  maps to  W[s*32 + (lane>>4)*8 + e][ct*16 + (lane&15)]
__global__ void pack_w_kernel(const float* __restrict__ W,
                              unsigned short* __restrict__ w_hi,
                              unsigned short* __restrict__ w_lo) {
    int t = blockIdx.x * 256 + threadIdx.x;   // 0..4095
    if (t >= 8 * 8 * 64) return;
    int l  = t & 63;
    int ct = (t >> 6) & 7;
    int s  = t >> 9;
    int kbase = s * 32 + (l >> 4) * 8;
    int col   = ct * 16 + (l & 15);
    unsigned short hi[8], lo[8];
#pragma unroll
    for (int e = 0; e < 8; ++e) {
        float w = W[(size_t)(kbase + e) * HC + col];
        unsigned short h16 = bf16_rn(w);
        hi[e] = h16;
        lo[e] = bf16_rn(w - bf16_to_f32(h16));
    }
    size_t base = (size_t)t * 8;
#pragma unroll
    for (int e = 0; e < 8; ++e) { w_hi[base + e] = hi[e]; w_lo[base + e] = lo[e]; }
}

// ---------------- GEMM: h = x @ W via bf16 MFMA with hi/lo split ----------------
// 512 threads = 8 waves; wave w: row-tile rt = w&3 (16 rows), col-half = w>>2 (4 col-tiles)
__global__ __launch_bounds__(512) void gemm_mfma_kernel(const float* __restrict__ x,
                                                        const unsigned short* __restrict__ w_hi,
                                                        const unsigned short* __restrict__ w_lo,
                                                        float* __restrict__ h, int n) {
    const int tid = threadIdx.x;
    const int l = tid & 63;
    const int wv = tid >> 6;
    const int rt = wv & 3;
    const int chalf = wv >> 2;
    const int row0 = blockIdx.x * 64 + rt * 16;

    int arow = row0 + (l & 15);
    if (arow >= n) arow = n - 1;   // clamp; stores are guarded
    const float* xrow = x + (size_t)arow * IN_DIM + (l >> 4) * 8;

    f32x4 acc[4];
#pragma unroll
    for (int ct = 0; ct < 4; ++ct) acc[ct] = (f32x4){0.f, 0.f, 0.f, 0.f};

    for (int s = 0; s < 8; ++s) {
        float4 xa = *reinterpret_cast<const float4*>(xrow + s * 32);
        float4 xb = *reinterpret_cast<const float4*>(xrow + s * 32 + 4);
        float xs8[8] = {xa.x, xa.y, xa.z, xa.w, xb.x, xb.y, xb.z, xb.w};
        short8v a_hi, a_lo;
#pragma unroll
        for (int e = 0; e < 8; ++e) {
            unsigned short h16 = bf16_rn(xs8[e]);
            a_hi[e] = (short)h16;
            a_lo[e] = (short)bf16_rn(xs8[e] - bf16_to_f32(h16));
        }
#pragma unroll
        for (int ct = 0; ct < 4; ++ct) {
            int ctg = chalf * 4 + ct;
            size_t fo = ((size_t)(s * 8 + ctg) * 64 + l) * 8;
            short8v bh = *reinterpret_cast<const short8v*>(w_hi + fo);
            short8v bl = *reinterpret_cast<const short8v*>(w_lo + fo);
            acc[ct] = __builtin_amdgcn_mfma_f32_16x16x32_bf16(a_hi, bh, acc[ct], 0, 0, 0);
            acc[ct] = __builtin_amdgcn_mfma_f32_16x16x32_bf16(a_lo, bh, acc[ct], 0, 0, 0);
            acc[ct] = __builtin_amdgcn_mfma_f32_16x16x32_bf16(a_hi, bl, acc[ct], 0, 0, 0);
        }
    }

    // epilogue: C layout col = lane&15, row = (lane>>4)*4 + reg
#pragma unroll
    for (int ct = 0; ct < 4; ++ct) {
        int col = (chalf * 4 + ct) * 16 + (l & 15);
#pragma unroll
        for (int r = 0; r < 4; ++r) {
            int row = row0 + (l >> 4) * 4 + r;
            if (row < n) h[(size_t)row * HC + col] = acc[ct][r];
        }
    }
}

// ---------------- per-node attention logits ----------------
__global__ void alpha_kernel(const float* __restrict__ h,
                             const float* __restrict__ a_src,
                             const float* __restrict__ a_dst,
                             float* __restrict__ alpha_s,
                             float* __restrict__ alpha_d, int n) {
    int gid = blockIdx.x * 256 + threadIdx.x;    // one per (node, head)
    if (gid >= n * NHEAD) return;
    int head = gid & 3;
    int node = gid >> 2;
    const float4* h4  = reinterpret_cast<const float4*>(h + (size_t)node * HC + head * CDIM);
    const float4* as4 = reinterpret_cast<const float4*>(a_src + head * CDIM);
    const float4* ad4 = reinterpret_cast<const float4*>(a_dst + head * CDIM);
    float ss = 0.f, sd = 0.f;
#pragma unroll
    for (int i = 0; i < 8; ++i) {
        float4 hv = h4[i], av = as4[i], dv = ad4[i];
        ss += hv.x * av.x + hv.y * av.y + hv.z * av.z + hv.w * av.w;
        sd += hv.x * dv.x + hv.y * dv.y + hv.z * dv.z + hv.w * dv.w;
    }
    alpha_s[gid] = ss;
    alpha_d[gid] = sd;
}

// ---------------- CSR build ----------------
__global__ void init_deg_kernel(int* __restrict__ deg, int n) {
    int i = blockIdx.x * 256 + threadIdx.x;
    if (i < n) deg[i] = 1;   // self-loop
}

__global__ void count_deg_kernel(const int* __restrict__ ei, int* __restrict__ deg, int E) {
    int i = blockIdx.x * 256 + threadIdx.x;
    if (i < E) atomicAdd(&deg[ei[E + i]], 1);
}

// scan1: 1024 elems/block (256 thr x 4), exclusive within block, block total out
__global__ __launch_bounds__(256) void scan1_kernel(const int* __restrict__ deg,
                                                    int* __restrict__ row_start,
                                                    int* __restrict__ blk_sums, int n) {
    __shared__ int warp_sums[4];
    int t = threadIdx.x;
    int base = blockIdx.x * 1024 + t * 4;
    int v[4];
#pragma unroll
    for (int i = 0; i < 4; ++i) v[i] = (base + i < n) ? deg[base + i] : 0;
    int tsum = v[0] + v[1] + v[2] + v[3];
    int lane = t & 63, w = t >> 6;
    int x = tsum;
    for (int off = 1; off < 64; off <<= 1) {
        int y = __shfl_up(x, off);
        if (lane >= off) x += y;
    }
    if (lane == 63) warp_sums[w] = x;
    __syncthreads();
    int wo = 0;
    for (int i = 0; i < w; ++i) wo += warp_sums[i];
    int run = wo + x - tsum;   // exclusive prefix for this thread
#pragma unroll
    for (int i = 0; i < 4; ++i) {
        if (base + i < n) row_start[base + i] = run;
        run += v[i];
    }
    if (t == 255) blk_sums[blockIdx.x] = wo + x;
}

// scan2: single block, exclusive scan of blk_sums (nb <= 256)
__global__ __launch_bounds__(256) void scan2_kernel(int* __restrict__ bs, int nb) {
    __shared__ int warp_sums[4];
    int t = threadIdx.x;
    int v = (t < nb) ? bs[t] : 0;
    int lane = t & 63, w = t >> 6;
    int x = v;
    for (int off = 1; off < 64; off <<= 1) {
        int y = __shfl_up(x, off);
        if (lane >= off) x += y;
    }
    if (lane == 63) warp_sums[w] = x;
    __syncthreads();
    int wo = 0;
    for (int i = 0; i < w; ++i) wo += warp_sums[i];
    if (t < nb) bs[t] = wo + x - v;
}

__global__ void scan3_kernel(int* __restrict__ row_start, const int* __restrict__ bs, int n) {
    int i = blockIdx.x * 256 + threadIdx.x;
    if (i < n) row_start[i] += bs[i >> 10];
}

__global__ void fill_kernel(const int* __restrict__ ei, const int* __restrict__ row_start,
                            int* __restrict__ cursor, int* __restrict__ csr_src,
                            int E, int n) {
    int i = blockIdx.x * 256 + threadIdx.x;
    if (i >= E + n) return;
    int src, dst;
    if (i < E) { src = ei[i]; dst = ei[E + i]; }
    else       { src = dst = i - E; }
    int pos = row_start[dst] + atomicAdd(&cursor[dst], 1);
    csr_src[pos] = src;
}

// ---------------- fused gather: softmax + weighted sum + bias + tanh ----------------
__global__ __launch_bounds__(256) void gather_kernel(const int* __restrict__ row_start,
                                                     const int* __restrict__ deg,
                                                     const int* __restrict__ csr_src,
                                                     const float* __restrict__ alpha_s,
                                                     const float* __restrict__ alpha_d,
                                                     const float* __restrict__ h,
                                                     const float* __restrict__ bias,
                                                     float* __restrict__ out, int n) {
    int lane = threadIdx.x & 63;
    int v = blockIdx.x * 4 + (threadIdx.x >> 6);
    if (v >= n) return;
    int start = row_start[v];
    int cnt = deg[v];

    float4 ad = *reinterpret_cast<const float4*>(alpha_d + (size_t)v * 4);

    // pass 1: softmax denominators (4 heads), edges strided over lanes
    float s0 = 0.f, s1 = 0.f, s2 = 0.f, s3 = 0.f;
    for (int j = lane; j < cnt; j += 64) {
        int src = csr_src[start + j];
        float4 as = *reinterpret_cast<const float4*>(alpha_s + (size_t)src * 4);
        float e0 = as.x + ad.x, e1 = as.y + ad.y, e2 = as.z + ad.z, e3 = as.w + ad.w;
        e0 = e0 > 0.f ? e0 : NEG * e0;
        e1 = e1 > 0.f ? e1 : NEG * e1;
        e2 = e2 > 0.f ? e2 : NEG * e2;
        e3 = e3 > 0.f ? e3 : NEG * e3;
        s0 += __expf(e0); s1 += __expf(e1); s2 += __expf(e2); s3 += __expf(e3);
    }
#pragma unroll
    for (int off = 32; off > 0; off >>= 1) {
        s0 += __shfl_xor(s0, off);
        s1 += __shfl_xor(s1, off);
        s2 += __shfl_xor(s2, off);
        s3 += __shfl_xor(s3, off);
    }
    float i0 = 1.f / (s0 + 1e-16f), i1 = 1.f / (s1 + 1e-16f);
    float i2 = 1.f / (s2 + 1e-16f), i3 = 1.f / (s3 + 1e-16f);

    float invH = (lane < 32) ? ((lane < 16) ? i0 : i1) : ((lane < 48) ? i2 : i3);
    float adH  = (lane < 32) ? ((lane < 16) ? ad.x : ad.y) : ((lane < 48) ? ad.z : ad.w);
    int head = lane >> 4;

    // pass 2: weighted accumulate, lane's 2 channels
    float accx = 0.f, accy = 0.f;
    const float2* h2 = reinterpret_cast<const float2*>(h);
    for (int j = 0; j < cnt; ++j) {
        int src = csr_src[start + j];                 // wave-broadcast load
        float as = alpha_s[(size_t)src * 4 + head];   // 16-lane broadcast
        float e = as + adH;
        e = e > 0.f ? e : NEG * e;
        float w = __expf(e) * invH;
        float2 hv = h2[(size_t)src * 64 + lane];      // coalesced 512B/wave
        accx = fmaf(w, hv.x, accx);
        accy = fmaf(w, hv.y, accy);
    }
    float2 b = reinterpret_cast<const float2*>(bias)[lane];
    float2 o;
    o.x = tanhf(accx + b.x);
    o.y = tanhf(accy + b.y);
    reinterpret_cast<float2*>(out)[(size_t)v * 64 + lane] = o;
}

extern "C" void kernel_launch(void* const* d_in, const int* in_sizes, int n_in,
                              void* d_out, int out_size, void* d_ws, size_t ws_size,
                              hipStream_t stream) {
    const float* x     = (const float*)d_in[0];
    const float* W     = (const float*)d_in[1];
    const float* a_src = (const float*)d_in[2];
    const float* a_dst = (const float*)d_in[3];
    const float* bias  = (const float*)d_in[4];
    const int*   ei    = (const int*)d_in[5];

    const int n = in_sizes[0] / IN_DIM;        // 100000
    const int E = in_sizes[5] / 2;             // 1000000
    const int tot = E + n;

    float* ws = (float*)d_ws;
    size_t off = 0;
    float* h       = ws + off; off += (size_t)n * HC;          // 12.8M
    float* alpha_s = ws + off; off += (size_t)n * NHEAD;
    float* alpha_d = ws + off; off += (size_t)n * NHEAD;
    unsigned short* w_hi = (unsigned short*)(ws + off); off += 16384 / 2 * 2;  // 32768 ushorts = 16384 floats
    unsigned short* w_lo = (unsigned short*)(ws + off); off += 16384;
    // (w_hi consumed 16384 floats: fix bookkeeping precisely)
    // recompute offsets cleanly below
    off = (size_t)n * HC + 2 * (size_t)n * NHEAD;
    w_hi = (unsigned short*)(ws + off); off += 16384;   // 32768 ushorts
    w_lo = (unsigned short*)(ws + off); off += 16384;
    int* ibase     = (int*)(ws + off);
    int* deg       = ibase;                    // n
    int* row_start = ibase + n;                // n
    int* cursor    = ibase + 2 * (size_t)n;    // n
    int* blk_sums  = ibase + 3 * (size_t)n;    // <=256
    int* csr_src   = ibase + 3 * (size_t)n + 256;  // E+n

    float* out = (float*)d_out;

    const int nb = (n + 1023) / 1024;          // scan blocks

    hipMemsetAsync(cursor, 0, (size_t)n * sizeof(int), stream);

    pack_w_kernel<<<16, 256, 0, stream>>>(W, w_hi, w_lo);
    gemm_mfma_kernel<<<(n + 63) / 64, 512, 0, stream>>>(x, w_hi, w_lo, h, n);
    alpha_kernel<<<(n * NHEAD + 255) / 256, 256, 0, stream>>>(h, a_src, a_dst, alpha_s, alpha_d, n);

    init_deg_kernel<<<(n + 255) / 256, 256, 0, stream>>>(deg, n);
    count_deg_kernel<<<(E + 255) / 256, 256, 0, stream>>>(ei, deg, E);
    scan1_kernel<<<nb, 256, 0, stream>>>(deg, row_start, blk_sums, n);
    scan2_kernel<<<1, 256, 0, stream>>>(blk_sums, nb);
    scan3_kernel<<<(n + 255) / 256, 256, 0, stream>>>(row_start, blk_sums, n);
    fill_kernel<<<(tot + 255) / 256, 256, 0, stream>>>(ei, row_start, cursor, csr_src, E, n);

    gather_kernel<<<(n + 3) / 4, 256, 0, stream>>>(row_start, deg, csr_src,
                                                   alpha_s, alpha_d, h, bias, out, n);
}

// Round 4
// 309.256 us; speedup vs baseline: 2.9560x; 1.1209x over previous
//
#include <hip/hip_runtime.h>

#define IN_DIM 256
#define HC     128   // H*C
#define NHEAD  4
#define CDIM   32
#define NEG    0.2f

typedef __attribute__((ext_vector_type(8))) short short8v;
typedef __attribute__((ext_vector_type(4))) float f32x4;

__device__ __forceinline__ unsigned short bf16_rn(float f) {
    unsigned u = __builtin_bit_cast(unsigned, f);
    return (unsigned short)((u + 0x7fffu + ((u >> 16) & 1u)) >> 16);
}
__device__ __forceinline__ float bf16_to_f32(unsigned short b) {
    unsigned u = ((unsigned)b) << 16;
    return __builtin_bit_cast(float, u);
}

// ---------------- pack W into MFMA fragment order, hi/lo bf16 ----------------
// frag index: ((s*8 + ct)*64 + lane)*8 + e  maps to  W[s*32 + (lane>>4)*8 + e][ct*16 + (lane&15)]
__global__ void pack_w_kernel(const float* __restrict__ W,
                              unsigned short* __restrict__ w_hi,
                              unsigned short* __restrict__ w_lo) {
    int t = blockIdx.x * 256 + threadIdx.x;   // 0..4095
    if (t >= 8 * 8 * 64) return;
    int l  = t & 63;
    int ct = (t >> 6) & 7;
    int s  = t >> 9;
    int kbase = s * 32 + (l >> 4) * 8;
    int col   = ct * 16 + (l & 15);
    unsigned short hi[8], lo[8];
#pragma unroll
    for (int e = 0; e < 8; ++e) {
        float w = W[(size_t)(kbase + e) * HC + col];
        unsigned short h16 = bf16_rn(w);
        hi[e] = h16;
        lo[e] = bf16_rn(w - bf16_to_f32(h16));
    }
    size_t base = (size_t)t * 8;
#pragma unroll
    for (int e = 0; e < 8; ++e) { w_hi[base + e] = hi[e]; w_lo[base + e] = lo[e]; }
}

// ---------------- GEMM: h = x @ W via bf16 MFMA with hi/lo split ----------------
// 512 threads = 8 waves; wave w: row-tile rt = w&3 (16 rows), col-half = w>>2 (4 col-tiles)
// Epilogue: h stored bf16; alpha_s/alpha_d computed from fp32 acc via 16-lane reduce.
__global__ __launch_bounds__(512) void gemm_mfma_kernel(const float* __restrict__ x,
                                                        const unsigned short* __restrict__ w_hi,
                                                        const unsigned short* __restrict__ w_lo,
                                                        const float* __restrict__ a_src,
                                                        const float* __restrict__ a_dst,
                                                        unsigned short* __restrict__ h_bf,
                                                        float* __restrict__ alpha_s,
                                                        float* __restrict__ alpha_d, int n) {
    const int tid = threadIdx.x;
    const int l = tid & 63;
    const int wv = tid >> 6;
    const int rt = wv & 3;
    const int chalf = wv >> 2;
    const int row0 = blockIdx.x * 64 + rt * 16;

    int arow = row0 + (l & 15);
    if (arow >= n) arow = n - 1;   // clamp; stores are guarded
    const float* xrow = x + (size_t)arow * IN_DIM + (l >> 4) * 8;

    f32x4 acc[4];
#pragma unroll
    for (int ct = 0; ct < 4; ++ct) acc[ct] = (f32x4){0.f, 0.f, 0.f, 0.f};

    for (int s = 0; s < 8; ++s) {
        float4 xa = *reinterpret_cast<const float4*>(xrow + s * 32);
        float4 xb = *reinterpret_cast<const float4*>(xrow + s * 32 + 4);
        float xs8[8] = {xa.x, xa.y, xa.z, xa.w, xb.x, xb.y, xb.z, xb.w};
        short8v a_hi, a_lo;
#pragma unroll
        for (int e = 0; e < 8; ++e) {
            unsigned short h16 = bf16_rn(xs8[e]);
            a_hi[e] = (short)h16;
            a_lo[e] = (short)bf16_rn(xs8[e] - bf16_to_f32(h16));
        }
#pragma unroll
        for (int ct = 0; ct < 4; ++ct) {
            int ctg = chalf * 4 + ct;
            size_t fo = ((size_t)(s * 8 + ctg) * 64 + l) * 8;
            short8v bh = *reinterpret_cast<const short8v*>(w_hi + fo);
            short8v bl = *reinterpret_cast<const short8v*>(w_lo + fo);
            acc[ct] = __builtin_amdgcn_mfma_f32_16x16x32_bf16(a_hi, bh, acc[ct], 0, 0, 0);
            acc[ct] = __builtin_amdgcn_mfma_f32_16x16x32_bf16(a_lo, bh, acc[ct], 0, 0, 0);
            acc[ct] = __builtin_amdgcn_mfma_f32_16x16x32_bf16(a_hi, bl, acc[ct], 0, 0, 0);
        }
    }

    // ---- epilogue 1: store h as bf16. C layout: col = lane&15, row = (lane>>4)*4 + reg
#pragma unroll
    for (int ct = 0; ct < 4; ++ct) {
        int col = (chalf * 4 + ct) * 16 + (l & 15);
#pragma unroll
        for (int r = 0; r < 4; ++r) {
            int row = row0 + (l >> 4) * 4 + r;
            if (row < n) h_bf[(size_t)row * HC + col] = bf16_rn(acc[ct][r]);
        }
    }

    // ---- epilogue 2: fused alpha logits.
    // cols for ct 0,1 -> head chalf*2; ct 2,3 -> head chalf*2+1 (flat a index == col)
    float as_c[4], ad_c[4];
#pragma unroll
    for (int ct = 0; ct < 4; ++ct) {
        int col = (chalf * 4 + ct) * 16 + (l & 15);
        as_c[ct] = a_src[col];
        ad_c[ct] = a_dst[col];
    }
#pragma unroll
    for (int r = 0; r < 4; ++r) {
        float pS0 = acc[0][r] * as_c[0] + acc[1][r] * as_c[1];
        float pS1 = acc[2][r] * as_c[2] + acc[3][r] * as_c[3];
        float pD0 = acc[0][r] * ad_c[0] + acc[1][r] * ad_c[1];
        float pD1 = acc[2][r] * ad_c[2] + acc[3][r] * ad_c[3];
#pragma unroll
        for (int m = 1; m < 16; m <<= 1) {
            pS0 += __shfl_xor(pS0, m);
            pS1 += __shfl_xor(pS1, m);
            pD0 += __shfl_xor(pD0, m);
            pD1 += __shfl_xor(pD1, m);
        }
        if ((l & 15) == 0) {
            int row = row0 + (l >> 4) * 4 + r;
            if (row < n) {
                int hb2 = chalf * 2;
                alpha_s[(size_t)row * 4 + hb2]     = pS0;
                alpha_s[(size_t)row * 4 + hb2 + 1] = pS1;
                alpha_d[(size_t)row * 4 + hb2]     = pD0;
                alpha_d[(size_t)row * 4 + hb2 + 1] = pD1;
            }
        }
    }
}

// ---------------- CSR build ----------------
__global__ void init_deg_kernel(int* __restrict__ deg, int n) {
    int i = blockIdx.x * 256 + threadIdx.x;
    if (i < n) deg[i] = 1;   // self-loop
}

__global__ void count_deg_kernel(const int* __restrict__ ei, int* __restrict__ deg, int E) {
    int i = blockIdx.x * 256 + threadIdx.x;
    if (i < E) atomicAdd(&deg[ei[E + i]], 1);
}

// scan1: 1024 elems/block (256 thr x 4), exclusive within block, block total out
__global__ __launch_bounds__(256) void scan1_kernel(const int* __restrict__ deg,
                                                    int* __restrict__ row_start,
                                                    int* __restrict__ blk_sums, int n) {
    __shared__ int warp_sums[4];
    int t = threadIdx.x;
    int base = blockIdx.x * 1024 + t * 4;
    int v[4];
#pragma unroll
    for (int i = 0; i < 4; ++i) v[i] = (base + i < n) ? deg[base + i] : 0;
    int tsum = v[0] + v[1] + v[2] + v[3];
    int lane = t & 63, w = t >> 6;
    int x = tsum;
    for (int off = 1; off < 64; off <<= 1) {
        int y = __shfl_up(x, off);
        if (lane >= off) x += y;
    }
    if (lane == 63) warp_sums[w] = x;
    __syncthreads();
    int wo = 0;
    for (int i = 0; i < w; ++i) wo += warp_sums[i];
    int run = wo + x - tsum;   // exclusive prefix for this thread
#pragma unroll
    for (int i = 0; i < 4; ++i) {
        if (base + i < n) row_start[base + i] = run;
        run += v[i];
    }
    if (t == 255) blk_sums[blockIdx.x] = wo + x;
}

// scan2: single block, exclusive scan of blk_sums (nb <= 256)
__global__ __launch_bounds__(256) void scan2_kernel(int* __restrict__ bs, int nb) {
    __shared__ int warp_sums[4];
    int t = threadIdx.x;
    int v = (t < nb) ? bs[t] : 0;
    int lane = t & 63, w = t >> 6;
    int x = v;
    for (int off = 1; off < 64; off <<= 1) {
        int y = __shfl_up(x, off);
        if (lane >= off) x += y;
    }
    if (lane == 63) warp_sums[w] = x;
    __syncthreads();
    int wo = 0;
    for (int i = 0; i < w; ++i) wo += warp_sums[i];
    if (t < nb) bs[t] = wo + x - v;
}

__global__ void scan3_kernel(int* __restrict__ row_start, const int* __restrict__ bs, int n) {
    int i = blockIdx.x * 256 + threadIdx.x;
    if (i < n) row_start[i] += bs[i >> 10];
}

__global__ void fill_kernel(const int* __restrict__ ei, const int* __restrict__ row_start,
                            int* __restrict__ cursor, int* __restrict__ csr_src,
                            int E, int n) {
    int i = blockIdx.x * 256 + threadIdx.x;
    if (i >= E + n) return;
    int src, dst;
    if (i < E) { src = ei[i]; dst = ei[E + i]; }
    else       { src = dst = i - E; }
    int pos = row_start[dst] + atomicAdd(&cursor[dst], 1);
    csr_src[pos] = src;
}

// ---------------- fused gather: softmax + weighted sum + bias + tanh ----------------
// one wave per dst node; lane owns channels {2*lane, 2*lane+1} (head = lane>>4)
__global__ __launch_bounds__(256) void gather_kernel(const int* __restrict__ row_start,
                                                     const int* __restrict__ deg,
                                                     const int* __restrict__ csr_src,
                                                     const float* __restrict__ alpha_s,
                                                     const float* __restrict__ alpha_d,
                                                     const unsigned short* __restrict__ h_bf,
                                                     const float* __restrict__ bias,
                                                     float* __restrict__ out, int n) {
    int lane = threadIdx.x & 63;
    int v = blockIdx.x * 4 + (threadIdx.x >> 6);
    if (v >= n) return;
    int start = row_start[v];
    int cnt = deg[v];

    float4 ad = *reinterpret_cast<const float4*>(alpha_d + (size_t)v * 4);

    // pass 1: softmax denominators (4 heads), edges strided over lanes
    float s0 = 0.f, s1 = 0.f, s2 = 0.f, s3 = 0.f;
    for (int j = lane; j < cnt; j += 64) {
        int src = csr_src[start + j];
        float4 as = *reinterpret_cast<const float4*>(alpha_s + (size_t)src * 4);
        float e0 = as.x + ad.x, e1 = as.y + ad.y, e2 = as.z + ad.z, e3 = as.w + ad.w;
        e0 = e0 > 0.f ? e0 : NEG * e0;
        e1 = e1 > 0.f ? e1 : NEG * e1;
        e2 = e2 > 0.f ? e2 : NEG * e2;
        e3 = e3 > 0.f ? e3 : NEG * e3;
        s0 += __expf(e0); s1 += __expf(e1); s2 += __expf(e2); s3 += __expf(e3);
    }
#pragma unroll
    for (int off = 32; off > 0; off >>= 1) {
        s0 += __shfl_xor(s0, off);
        s1 += __shfl_xor(s1, off);
        s2 += __shfl_xor(s2, off);
        s3 += __shfl_xor(s3, off);
    }
    float i0 = 1.f / (s0 + 1e-16f), i1 = 1.f / (s1 + 1e-16f);
    float i2 = 1.f / (s2 + 1e-16f), i3 = 1.f / (s3 + 1e-16f);

    float invH = (lane < 32) ? ((lane < 16) ? i0 : i1) : ((lane < 48) ? i2 : i3);
    float adH  = (lane < 32) ? ((lane < 16) ? ad.x : ad.y) : ((lane < 48) ? ad.z : ad.w);
    int head = lane >> 4;

    // pass 2: weighted accumulate, lane's 2 channels (bf16 h, 4 B/lane/edge)
    float accx = 0.f, accy = 0.f;
    const unsigned* hb = reinterpret_cast<const unsigned*>(h_bf);
    for (int j = 0; j < cnt; ++j) {
        int src = csr_src[start + j];                 // wave-broadcast load
        float as = alpha_s[(size_t)src * 4 + head];   // 16-lane broadcast
        float e = as + adH;
        e = e > 0.f ? e : NEG * e;
        float w = __expf(e) * invH;
        unsigned hv = hb[(size_t)src * 64 + lane];    // coalesced 256B/wave
        float hx = bf16_to_f32((unsigned short)(hv & 0xffffu));
        float hy = bf16_to_f32((unsigned short)(hv >> 16));
        accx = fmaf(w, hx, accx);
        accy = fmaf(w, hy, accy);
    }
    float2 b = reinterpret_cast<const float2*>(bias)[lane];
    float2 o;
    o.x = tanhf(accx + b.x);
    o.y = tanhf(accy + b.y);
    reinterpret_cast<float2*>(out)[(size_t)v * 64 + lane] = o;
}

extern "C" void kernel_launch(void* const* d_in, const int* in_sizes, int n_in,
                              void* d_out, int out_size, void* d_ws, size_t ws_size,
                              hipStream_t stream) {
    const float* x     = (const float*)d_in[0];
    const float* W     = (const float*)d_in[1];
    const float* a_src = (const float*)d_in[2];
    const float* a_dst = (const float*)d_in[3];
    const float* bias  = (const float*)d_in[4];
    const int*   ei    = (const int*)d_in[5];

    const int n = in_sizes[0] / IN_DIM;        // 100000
    const int E = in_sizes[5] / 2;             // 1000000
    const int tot = E + n;

    float* ws = (float*)d_ws;
    size_t off = 0;
    unsigned short* h_bf = (unsigned short*)(ws + off); off += (size_t)n * HC / 2;  // n*128 ushorts
    float* alpha_s = ws + off; off += (size_t)n * NHEAD;
    float* alpha_d = ws + off; off += (size_t)n * NHEAD;
    unsigned short* w_hi = (unsigned short*)(ws + off); off += 16384;   // 32768 ushorts
    unsigned short* w_lo = (unsigned short*)(ws + off); off += 16384;
    int* ibase     = (int*)(ws + off);
    int* deg       = ibase;                    // n
    int* row_start = ibase + n;                // n
    int* cursor    = ibase + 2 * (size_t)n;    // n
    int* blk_sums  = ibase + 3 * (size_t)n;    // <=256
    int* csr_src   = ibase + 3 * (size_t)n + 256;  // E+n

    float* out = (float*)d_out;

    const int nb = (n + 1023) / 1024;          // scan blocks

    hipMemsetAsync(cursor, 0, (size_t)n * sizeof(int), stream);

    pack_w_kernel<<<16, 256, 0, stream>>>(W, w_hi, w_lo);
    gemm_mfma_kernel<<<(n + 63) / 64, 512, 0, stream>>>(x, w_hi, w_lo, a_src, a_dst,
                                                        h_bf, alpha_s, alpha_d, n);

    init_deg_kernel<<<(n + 255) / 256, 256, 0, stream>>>(deg, n);
    count_deg_kernel<<<(E + 255) / 256, 256, 0, stream>>>(ei, deg, E);
    scan1_kernel<<<nb, 256, 0, stream>>>(deg, row_start, blk_sums, n);
    scan2_kernel<<<1, 256, 0, stream>>>(blk_sums, nb);
    scan3_kernel<<<(n + 255) / 256, 256, 0, stream>>>(row_start, blk_sums, n);
    fill_kernel<<<(tot + 255) / 256, 256, 0, stream>>>(ei, row_start, cursor, csr_src, E, n);

    gather_kernel<<<(n + 3) / 4, 256, 0, stream>>>(row_start, deg, csr_src,
                                                   alpha_s, alpha_d, h_bf, bias, out, n);
}

// Round 5
// 258.310 us; speedup vs baseline: 3.5390x; 1.1972x over previous
//
#include <hip/hip_runtime.h>

#define IN_DIM 256
#define HC     128   // H*C
#define NHEAD  4
#define CDIM   32
#define NEG    0.2f
#define CAP    256   // per-wave LDS edge-weight capacity

typedef __attribute__((ext_vector_type(8))) short short8v;
typedef __attribute__((ext_vector_type(4))) float f32x4;

__device__ __forceinline__ unsigned short bf16_rn(float f) {
    unsigned u = __builtin_bit_cast(unsigned, f);
    return (unsigned short)((u + 0x7fffu + ((u >> 16) & 1u)) >> 16);
}
__device__ __forceinline__ float bf16_to_f32(unsigned short b) {
    unsigned u = ((unsigned)b) << 16;
    return __builtin_bit_cast(float, u);
}

// ---------------- pack W into MFMA fragment order, hi/lo bf16 ----------------
__global__ void pack_w_kernel(const float* __restrict__ W,
                              unsigned short* __restrict__ w_hi,
                              unsigned short* __restrict__ w_lo) {
    int t = blockIdx.x * 256 + threadIdx.x;   // 0..4095
    if (t >= 8 * 8 * 64) return;
    int l  = t & 63;
    int ct = (t >> 6) & 7;
    int s  = t >> 9;
    int kbase = s * 32 + (l >> 4) * 8;
    int col   = ct * 16 + (l & 15);
    unsigned short hi[8], lo[8];
#pragma unroll
    for (int e = 0; e < 8; ++e) {
        float w = W[(size_t)(kbase + e) * HC + col];
        unsigned short h16 = bf16_rn(w);
        hi[e] = h16;
        lo[e] = bf16_rn(w - bf16_to_f32(h16));
    }
    size_t base = (size_t)t * 8;
#pragma unroll
    for (int e = 0; e < 8; ++e) { w_hi[base + e] = hi[e]; w_lo[base + e] = lo[e]; }
}

// ---------------- GEMM: h = x @ W via bf16 MFMA with hi/lo split ----------------
__global__ __launch_bounds__(512) void gemm_mfma_kernel(const float* __restrict__ x,
                                                        const unsigned short* __restrict__ w_hi,
                                                        const unsigned short* __restrict__ w_lo,
                                                        const float* __restrict__ a_src,
                                                        const float* __restrict__ a_dst,
                                                        unsigned short* __restrict__ h_bf,
                                                        float* __restrict__ alpha_s,
                                                        float* __restrict__ alpha_d, int n) {
    const int tid = threadIdx.x;
    const int l = tid & 63;
    const int wv = tid >> 6;
    const int rt = wv & 3;
    const int chalf = wv >> 2;
    const int row0 = blockIdx.x * 64 + rt * 16;

    int arow = row0 + (l & 15);
    if (arow >= n) arow = n - 1;   // clamp; stores are guarded
    const float* xrow = x + (size_t)arow * IN_DIM + (l >> 4) * 8;

    f32x4 acc[4];
#pragma unroll
    for (int ct = 0; ct < 4; ++ct) acc[ct] = (f32x4){0.f, 0.f, 0.f, 0.f};

    for (int s = 0; s < 8; ++s) {
        float4 xa = *reinterpret_cast<const float4*>(xrow + s * 32);
        float4 xb = *reinterpret_cast<const float4*>(xrow + s * 32 + 4);
        float xs8[8] = {xa.x, xa.y, xa.z, xa.w, xb.x, xb.y, xb.z, xb.w};
        short8v a_hi, a_lo;
#pragma unroll
        for (int e = 0; e < 8; ++e) {
            unsigned short h16 = bf16_rn(xs8[e]);
            a_hi[e] = (short)h16;
            a_lo[e] = (short)bf16_rn(xs8[e] - bf16_to_f32(h16));
        }
#pragma unroll
        for (int ct = 0; ct < 4; ++ct) {
            int ctg = chalf * 4 + ct;
            size_t fo = ((size_t)(s * 8 + ctg) * 64 + l) * 8;
            short8v bh = *reinterpret_cast<const short8v*>(w_hi + fo);
            short8v bl = *reinterpret_cast<const short8v*>(w_lo + fo);
            acc[ct] = __builtin_amdgcn_mfma_f32_16x16x32_bf16(a_hi, bh, acc[ct], 0, 0, 0);
            acc[ct] = __builtin_amdgcn_mfma_f32_16x16x32_bf16(a_lo, bh, acc[ct], 0, 0, 0);
            acc[ct] = __builtin_amdgcn_mfma_f32_16x16x32_bf16(a_hi, bl, acc[ct], 0, 0, 0);
        }
    }

    // ---- epilogue 1: store h as bf16. C layout: col = lane&15, row = (lane>>4)*4 + reg
#pragma unroll
    for (int ct = 0; ct < 4; ++ct) {
        int col = (chalf * 4 + ct) * 16 + (l & 15);
#pragma unroll
        for (int r = 0; r < 4; ++r) {
            int row = row0 + (l >> 4) * 4 + r;
            if (row < n) h_bf[(size_t)row * HC + col] = bf16_rn(acc[ct][r]);
        }
    }

    // ---- epilogue 2: fused alpha logits
    float as_c[4], ad_c[4];
#pragma unroll
    for (int ct = 0; ct < 4; ++ct) {
        int col = (chalf * 4 + ct) * 16 + (l & 15);
        as_c[ct] = a_src[col];
        ad_c[ct] = a_dst[col];
    }
#pragma unroll
    for (int r = 0; r < 4; ++r) {
        float pS0 = acc[0][r] * as_c[0] + acc[1][r] * as_c[1];
        float pS1 = acc[2][r] * as_c[2] + acc[3][r] * as_c[3];
        float pD0 = acc[0][r] * ad_c[0] + acc[1][r] * ad_c[1];
        float pD1 = acc[2][r] * ad_c[2] + acc[3][r] * ad_c[3];
#pragma unroll
        for (int m = 1; m < 16; m <<= 1) {
            pS0 += __shfl_xor(pS0, m);
            pS1 += __shfl_xor(pS1, m);
            pD0 += __shfl_xor(pD0, m);
            pD1 += __shfl_xor(pD1, m);
        }
        if ((l & 15) == 0) {
            int row = row0 + (l >> 4) * 4 + r;
            if (row < n) {
                int hb2 = chalf * 2;
                alpha_s[(size_t)row * 4 + hb2]     = pS0;
                alpha_s[(size_t)row * 4 + hb2 + 1] = pS1;
                alpha_d[(size_t)row * 4 + hb2]     = pD0;
                alpha_d[(size_t)row * 4 + hb2 + 1] = pD1;
            }
        }
    }
}

// ---------------- CSR build (real edges only; self-loop implicit) ----------------
__global__ void count_deg_kernel(const int* __restrict__ ei, int* __restrict__ deg, int E) {
    int i = blockIdx.x * 256 + threadIdx.x;
    if (i < E) atomicAdd(&deg[ei[E + i]], 1);
}

// scan1: 1024 elems/block (256 thr x 4), exclusive within block, block total out
__global__ __launch_bounds__(256) void scan1_kernel(const int* __restrict__ deg,
                                                    int* __restrict__ row_start,
                                                    int* __restrict__ blk_sums, int n) {
    __shared__ int warp_sums[4];
    int t = threadIdx.x;
    int base = blockIdx.x * 1024 + t * 4;
    int v[4];
#pragma unroll
    for (int i = 0; i < 4; ++i) v[i] = (base + i < n) ? deg[base + i] : 0;
    int tsum = v[0] + v[1] + v[2] + v[3];
    int lane = t & 63, w = t >> 6;
    int x = tsum;
    for (int off = 1; off < 64; off <<= 1) {
        int y = __shfl_up(x, off);
        if (lane >= off) x += y;
    }
    if (lane == 63) warp_sums[w] = x;
    __syncthreads();
    int wo = 0;
    for (int i = 0; i < w; ++i) wo += warp_sums[i];
    int run = wo + x - tsum;   // exclusive prefix for this thread
#pragma unroll
    for (int i = 0; i < 4; ++i) {
        if (base + i < n) row_start[base + i] = run;
        run += v[i];
    }
    if (t == 255) blk_sums[blockIdx.x] = wo + x;
}

__global__ __launch_bounds__(256) void scan2_kernel(int* __restrict__ bs, int nb) {
    __shared__ int warp_sums[4];
    int t = threadIdx.x;
    int v = (t < nb) ? bs[t] : 0;
    int lane = t & 63, w = t >> 6;
    int x = v;
    for (int off = 1; off < 64; off <<= 1) {
        int y = __shfl_up(x, off);
        if (lane >= off) x += y;
    }
    if (lane == 63) warp_sums[w] = x;
    __syncthreads();
    int wo = 0;
    for (int i = 0; i < w; ++i) wo += warp_sums[i];
    if (t < nb) bs[t] = wo + x - v;
}

__global__ void scan3_kernel(int* __restrict__ row_start, const int* __restrict__ bs, int n) {
    int i = blockIdx.x * 256 + threadIdx.x;
    if (i < n) row_start[i] += bs[i >> 10];
}

__global__ void fill_kernel(const int* __restrict__ ei, const int* __restrict__ row_start,
                            int* __restrict__ cursor, int* __restrict__ csr_src, int E) {
    int i = blockIdx.x * 256 + threadIdx.x;
    if (i >= E) return;
    int src = ei[i];
    int dst = ei[E + i];
    int pos = row_start[dst] + atomicAdd(&cursor[dst], 1);
    csr_src[pos] = src;
}

// ---------------- fused gather: softmax + weighted sum + bias + tanh ----------------
// one wave per dst node; lane owns channels {2*lane, 2*lane+1} (head = lane>>4)
// pass 1 stores per-edge exp weights in LDS; pass 2 unrolled x4 for MLP.
__global__ __launch_bounds__(256) void gather_kernel(const int* __restrict__ row_start,
                                                     const int* __restrict__ deg,
                                                     const int* __restrict__ csr_src,
                                                     const float* __restrict__ alpha_s,
                                                     const float* __restrict__ alpha_d,
                                                     const unsigned short* __restrict__ h_bf,
                                                     const float* __restrict__ bias,
                                                     float* __restrict__ out, int n) {
    __shared__ float pbuf[4][CAP * 4];   // 16 KB
    int lane = threadIdx.x & 63;
    int wid  = threadIdx.x >> 6;
    int v = blockIdx.x * 4 + wid;
    if (v >= n) return;
    int start = row_start[v];
    int cnt = deg[v];            // real in-edges (self-loop implicit)
    float* wp = pbuf[wid];

    float4 ad  = *reinterpret_cast<const float4*>(alpha_d + (size_t)v * 4);
    float4 asv = *reinterpret_cast<const float4*>(alpha_s + (size_t)v * 4);

    // pass 1: per-edge exp weights -> LDS; accumulate denominators
    float s0 = 0.f, s1 = 0.f, s2 = 0.f, s3 = 0.f;
    for (int j = lane; j < cnt; j += 64) {
        int src = csr_src[start + j];
        float4 as = *reinterpret_cast<const float4*>(alpha_s + (size_t)src * 4);
        float e0 = as.x + ad.x, e1 = as.y + ad.y, e2 = as.z + ad.z, e3 = as.w + ad.w;
        e0 = e0 > 0.f ? e0 : NEG * e0;
        e1 = e1 > 0.f ? e1 : NEG * e1;
        e2 = e2 > 0.f ? e2 : NEG * e2;
        e3 = e3 > 0.f ? e3 : NEG * e3;
        float p0 = __expf(e0), p1 = __expf(e1), p2 = __expf(e2), p3 = __expf(e3);
        if (j < CAP) *reinterpret_cast<float4*>(&wp[j * 4]) = make_float4(p0, p1, p2, p3);
        s0 += p0; s1 += p1; s2 += p2; s3 += p3;
    }
#pragma unroll
    for (int off = 32; off > 0; off >>= 1) {
        s0 += __shfl_xor(s0, off);
        s1 += __shfl_xor(s1, off);
        s2 += __shfl_xor(s2, off);
        s3 += __shfl_xor(s3, off);
    }
    // self-loop contribution (computed identically on all lanes)
    float se0 = asv.x + ad.x, se1 = asv.y + ad.y, se2 = asv.z + ad.z, se3 = asv.w + ad.w;
    se0 = se0 > 0.f ? se0 : NEG * se0;
    se1 = se1 > 0.f ? se1 : NEG * se1;
    se2 = se2 > 0.f ? se2 : NEG * se2;
    se3 = se3 > 0.f ? se3 : NEG * se3;
    float ps0 = __expf(se0), ps1 = __expf(se1), ps2 = __expf(se2), ps3 = __expf(se3);
    s0 += ps0; s1 += ps1; s2 += ps2; s3 += ps3;

    float i0 = 1.f / (s0 + 1e-16f), i1 = 1.f / (s1 + 1e-16f);
    float i2 = 1.f / (s2 + 1e-16f), i3 = 1.f / (s3 + 1e-16f);

    float invH  = (lane < 32) ? ((lane < 16) ? i0 : i1) : ((lane < 48) ? i2 : i3);
    float adH   = (lane < 32) ? ((lane < 16) ? ad.x : ad.y) : ((lane < 48) ? ad.z : ad.w);
    float pselfH= (lane < 32) ? ((lane < 16) ? ps0 : ps1) : ((lane < 48) ? ps2 : ps3);
    int head = lane >> 4;

    // pass 2: weighted accumulate, lane's 2 channels (bf16 h, 4 B/lane/edge), x4 unroll
    float accx = 0.f, accy = 0.f;
    const unsigned* hb = reinterpret_cast<const unsigned*>(h_bf);
    int m = cnt < CAP ? cnt : CAP;
    int j = 0;
    for (; j + 4 <= m; j += 4) {
        int sA = csr_src[start + j];
        int sB = csr_src[start + j + 1];
        int sC = csr_src[start + j + 2];
        int sD = csr_src[start + j + 3];
        float wA = wp[(j + 0) * 4 + head] * invH;
        float wB = wp[(j + 1) * 4 + head] * invH;
        float wC = wp[(j + 2) * 4 + head] * invH;
        float wD = wp[(j + 3) * 4 + head] * invH;
        unsigned hA = hb[(size_t)sA * 64 + lane];
        unsigned hB = hb[(size_t)sB * 64 + lane];
        unsigned hC = hb[(size_t)sC * 64 + lane];
        unsigned hD = hb[(size_t)sD * 64 + lane];
        accx = fmaf(wA, bf16_to_f32((unsigned short)(hA & 0xffffu)), accx);
        accy = fmaf(wA, bf16_to_f32((unsigned short)(hA >> 16)),     accy);
        accx = fmaf(wB, bf16_to_f32((unsigned short)(hB & 0xffffu)), accx);
        accy = fmaf(wB, bf16_to_f32((unsigned short)(hB >> 16)),     accy);
        accx = fmaf(wC, bf16_to_f32((unsigned short)(hC & 0xffffu)), accx);
        accy = fmaf(wC, bf16_to_f32((unsigned short)(hC >> 16)),     accy);
        accx = fmaf(wD, bf16_to_f32((unsigned short)(hD & 0xffffu)), accx);
        accy = fmaf(wD, bf16_to_f32((unsigned short)(hD >> 16)),     accy);
    }
    for (; j < m; ++j) {
        int src = csr_src[start + j];
        float w = wp[j * 4 + head] * invH;
        unsigned hv = hb[(size_t)src * 64 + lane];
        accx = fmaf(w, bf16_to_f32((unsigned short)(hv & 0xffffu)), accx);
        accy = fmaf(w, bf16_to_f32((unsigned short)(hv >> 16)),     accy);
    }
    for (; j < cnt; ++j) {   // overflow fallback: recompute weight
        int src = csr_src[start + j];
        float as = alpha_s[(size_t)src * 4 + head];
        float e = as + adH;
        e = e > 0.f ? e : NEG * e;
        float w = __expf(e) * invH;
        unsigned hv = hb[(size_t)src * 64 + lane];
        accx = fmaf(w, bf16_to_f32((unsigned short)(hv & 0xffffu)), accx);
        accy = fmaf(w, bf16_to_f32((unsigned short)(hv >> 16)),     accy);
    }
    // self loop
    {
        float w = pselfH * invH;
        unsigned hv = hb[(size_t)v * 64 + lane];
        accx = fmaf(w, bf16_to_f32((unsigned short)(hv & 0xffffu)), accx);
        accy = fmaf(w, bf16_to_f32((unsigned short)(hv >> 16)),     accy);
    }
    float2 b = reinterpret_cast<const float2*>(bias)[lane];
    float2 o;
    o.x = tanhf(accx + b.x);
    o.y = tanhf(accy + b.y);
    reinterpret_cast<float2*>(out)[(size_t)v * 64 + lane] = o;
}

extern "C" void kernel_launch(void* const* d_in, const int* in_sizes, int n_in,
                              void* d_out, int out_size, void* d_ws, size_t ws_size,
                              hipStream_t stream) {
    const float* x     = (const float*)d_in[0];
    const float* W     = (const float*)d_in[1];
    const float* a_src = (const float*)d_in[2];
    const float* a_dst = (const float*)d_in[3];
    const float* bias  = (const float*)d_in[4];
    const int*   ei    = (const int*)d_in[5];

    const int n = in_sizes[0] / IN_DIM;        // 100000
    const int E = in_sizes[5] / 2;             // 1000000

    float* ws = (float*)d_ws;
    size_t off = 0;
    unsigned short* h_bf = (unsigned short*)(ws + off); off += (size_t)n * HC / 2;
    float* alpha_s = ws + off; off += (size_t)n * NHEAD;
    float* alpha_d = ws + off; off += (size_t)n * NHEAD;
    unsigned short* w_hi = (unsigned short*)(ws + off); off += 16384;
    unsigned short* w_lo = (unsigned short*)(ws + off); off += 16384;
    int* ibase     = (int*)(ws + off);
    int* deg       = ibase;                    // n
    int* cursor    = ibase + n;                // n
    int* row_start = ibase + 2 * (size_t)n;    // n
    int* blk_sums  = ibase + 3 * (size_t)n;    // <=256
    int* csr_src   = ibase + 3 * (size_t)n + 256;  // E

    float* out = (float*)d_out;

    const int nb = (n + 1023) / 1024;          // scan blocks

    hipMemsetAsync(deg, 0, 2 * (size_t)n * sizeof(int), stream);  // deg + cursor

    pack_w_kernel<<<16, 256, 0, stream>>>(W, w_hi, w_lo);
    gemm_mfma_kernel<<<(n + 63) / 64, 512, 0, stream>>>(x, w_hi, w_lo, a_src, a_dst,
                                                        h_bf, alpha_s, alpha_d, n);

    count_deg_kernel<<<(E + 255) / 256, 256, 0, stream>>>(ei, deg, E);
    scan1_kernel<<<nb, 256, 0, stream>>>(deg, row_start, blk_sums, n);
    scan2_kernel<<<1, 256, 0, stream>>>(blk_sums, nb);
    scan3_kernel<<<(n + 255) / 256, 256, 0, stream>>>(row_start, blk_sums, n);
    fill_kernel<<<(E + 255) / 256, 256, 0, stream>>>(ei, row_start, cursor, csr_src, E);

    gather_kernel<<<(n + 3) / 4, 256, 0, stream>>>(row_start, deg, csr_src,
                                                   alpha_s, alpha_d, h_bf, bias, out, n);
}

// Round 6
// 242.114 us; speedup vs baseline: 3.7757x; 1.0669x over previous
//
#include <hip/hip_runtime.h>

#define IN_DIM 256
#define HC     128   // H*C
#define NHEAD  4
#define NEG    0.2f
#define CAP    256   // per-wave LDS edge-weight capacity (gather)
#define AS     264   // LDS row stride (ushorts) for staged A tiles (+8 pad -> 2-way max)

typedef __attribute__((ext_vector_type(8))) short short8v;
typedef __attribute__((ext_vector_type(4))) float f32x4;
typedef __attribute__((ext_vector_type(4))) unsigned short ushort4v;

__device__ __forceinline__ unsigned short bf16_rn(float f) {
    unsigned u = __builtin_bit_cast(unsigned, f);
    return (unsigned short)((u + 0x7fffu + ((u >> 16) & 1u)) >> 16);
}
__device__ __forceinline__ float bf16_to_f32(unsigned short b) {
    unsigned u = ((unsigned)b) << 16;
    return __builtin_bit_cast(float, u);
}

// ---------------- pack W (hi bf16 only) into MFMA fragment order ----------------
// w_hi[((s*8 + ct)*64 + l)*8 + e] = bf16(W[s*32 + (l>>4)*8 + e][ct*16 + (l&15)])
__global__ void pack_w_kernel(const float* __restrict__ W,
                              unsigned short* __restrict__ w_hi) {
    int t = blockIdx.x * 256 + threadIdx.x;   // 0..4095
    if (t >= 8 * 8 * 64) return;
    int l  = t & 63;
    int ct = (t >> 6) & 7;
    int s  = t >> 9;
    int kbase = s * 32 + (l >> 4) * 8;
    int col   = ct * 16 + (l & 15);
    size_t base = (size_t)t * 8;
#pragma unroll
    for (int e = 0; e < 8; ++e)
        w_hi[base + e] = bf16_rn(W[(size_t)(kbase + e) * HC + col]);
}

// ---------------- GEMM: h = x @ W via bf16 MFMA, x staged hi/lo in LDS ----------------
// Block: 64 rows, 512 threads = 8 waves. Wave wv: ct_g = wv&3 (head / 32 cols),
// rt_g = wv>>2 (32 rows). Each wave: 2 rt-tiles x 2 ct-tiles of 16x16 MFMA output.
__global__ __launch_bounds__(512) void gemm_mfma_kernel(const float* __restrict__ x,
                                                        const unsigned short* __restrict__ w_hi,
                                                        const float* __restrict__ a_src,
                                                        const float* __restrict__ a_dst,
                                                        unsigned short* __restrict__ h_bf,
                                                        float* __restrict__ alpha_s,
                                                        float* __restrict__ alpha_d, int n) {
    __shared__ unsigned short s_hi[64][AS];   // 33.8 KB
    __shared__ unsigned short s_lo[64][AS];   // 33.8 KB
    __shared__ float pS[64][4];
    __shared__ float pD[64][4];

    const int tid = threadIdx.x;
    const int l   = tid & 63;
    const int wv  = tid >> 6;
    const int row0 = blockIdx.x * 64;

    // ---- stage + convert: 64 rows x 256 cols, hi/lo bf16 -> LDS
    const float4* x4 = reinterpret_cast<const float4*>(x);
#pragma unroll
    for (int i = 0; i < 8; ++i) {
        int f = tid + i * 512;            // 0..4095
        int row = f >> 6, c4 = f & 63;
        float4 v = make_float4(0.f, 0.f, 0.f, 0.f);
        if (row0 + row < n) v = x4[(size_t)(row0 + row) * 64 + c4];
        float e[4] = {v.x, v.y, v.z, v.w};
        ushort4v hi, lo;
#pragma unroll
        for (int q = 0; q < 4; ++q) {
            unsigned short h16 = bf16_rn(e[q]);
            hi[q] = h16;
            lo[q] = bf16_rn(e[q] - bf16_to_f32(h16));
        }
        *reinterpret_cast<ushort4v*>(&s_hi[row][c4 * 4]) = hi;
        *reinterpret_cast<ushort4v*>(&s_lo[row][c4 * 4]) = lo;
    }
    __syncthreads();

    const int ct_g = wv & 3;
    const int rt_g = wv >> 2;
    const int rrow = l & 15;
    const int koff = (l >> 4) * 8;

    f32x4 acc[2][2];
#pragma unroll
    for (int a = 0; a < 2; ++a)
#pragma unroll
        for (int b = 0; b < 2; ++b) acc[a][b] = (f32x4){0.f, 0.f, 0.f, 0.f};

    for (int s = 0; s < 8; ++s) {
        short8v bh[2];
#pragma unroll
        for (int c = 0; c < 2; ++c) {
            int ct = ct_g * 2 + c;
            bh[c] = *reinterpret_cast<const short8v*>(w_hi + ((size_t)(s * 8 + ct) * 64 + l) * 8);
        }
#pragma unroll
        for (int r = 0; r < 2; ++r) {
            int arow = rt_g * 32 + r * 16 + rrow;
            short8v ah = *reinterpret_cast<const short8v*>(&s_hi[arow][koff + s * 32]);
            short8v al = *reinterpret_cast<const short8v*>(&s_lo[arow][koff + s * 32]);
#pragma unroll
            for (int c = 0; c < 2; ++c) {
                acc[r][c] = __builtin_amdgcn_mfma_f32_16x16x32_bf16(ah, bh[c], acc[r][c], 0, 0, 0);
                acc[r][c] = __builtin_amdgcn_mfma_f32_16x16x32_bf16(al, bh[c], acc[r][c], 0, 0, 0);
            }
        }
    }

    // ---- epilogue 1: h as bf16. C layout: col = lane&15 (of ct tile), row = (lane>>4)*4 + reg
#pragma unroll
    for (int r = 0; r < 2; ++r) {
#pragma unroll
        for (int c = 0; c < 2; ++c) {
            int col = (ct_g * 2 + c) * 16 + (l & 15);
#pragma unroll
            for (int q = 0; q < 4; ++q) {
                int row = row0 + rt_g * 32 + r * 16 + (l >> 4) * 4 + q;
                if (row < n) h_bf[(size_t)row * HC + col] = bf16_rn(acc[r][c][q]);
            }
        }
    }

    // ---- epilogue 2: alpha logits. Wave's 32 cols == head ct_g exactly.
    float asc[2], adc[2];
#pragma unroll
    for (int c = 0; c < 2; ++c) {
        int col = (ct_g * 2 + c) * 16 + (l & 15);
        asc[c] = a_src[col];
        adc[c] = a_dst[col];
    }
#pragma unroll
    for (int r = 0; r < 2; ++r) {
#pragma unroll
        for (int q = 0; q < 4; ++q) {
            float vS = acc[r][0][q] * asc[0] + acc[r][1][q] * asc[1];
            float vD = acc[r][0][q] * adc[0] + acc[r][1][q] * adc[1];
#pragma unroll
            for (int m = 1; m < 16; m <<= 1) {
                vS += __shfl_xor(vS, m);
                vD += __shfl_xor(vD, m);
            }
            if ((l & 15) == 0) {
                int rl = rt_g * 32 + r * 16 + (l >> 4) * 4 + q;
                pS[rl][ct_g] = vS;
                pD[rl][ct_g] = vD;
            }
        }
    }
    __syncthreads();
    if (tid < 256) {
        int rl = tid >> 2, h = tid & 3;
        int row = row0 + rl;
        if (row < n) {
            alpha_s[(size_t)row * 4 + h] = pS[rl][h];
            alpha_d[(size_t)row * 4 + h] = pD[rl][h];
        }
    }
}

// ---------------- CSR build (real edges only; self-loop implicit) ----------------
__global__ void count_deg_kernel(const int* __restrict__ ei, int* __restrict__ deg, int E) {
    int i = blockIdx.x * 256 + threadIdx.x;
    if (i < E) atomicAdd(&deg[ei[E + i]], 1);
}

__global__ __launch_bounds__(256) void scan1_kernel(const int* __restrict__ deg,
                                                    int* __restrict__ row_start,
                                                    int* __restrict__ blk_sums, int n) {
    __shared__ int warp_sums[4];
    int t = threadIdx.x;
    int base = blockIdx.x * 1024 + t * 4;
    int v[4];
#pragma unroll
    for (int i = 0; i < 4; ++i) v[i] = (base + i < n) ? deg[base + i] : 0;
    int tsum = v[0] + v[1] + v[2] + v[3];
    int lane = t & 63, w = t >> 6;
    int x = tsum;
    for (int off = 1; off < 64; off <<= 1) {
        int y = __shfl_up(x, off);
        if (lane >= off) x += y;
    }
    if (lane == 63) warp_sums[w] = x;
    __syncthreads();
    int wo = 0;
    for (int i = 0; i < w; ++i) wo += warp_sums[i];
    int run = wo + x - tsum;
#pragma unroll
    for (int i = 0; i < 4; ++i) {
        if (base + i < n) row_start[base + i] = run;
        run += v[i];
    }
    if (t == 255) blk_sums[blockIdx.x] = wo + x;
}

__global__ __launch_bounds__(256) void scan2_kernel(int* __restrict__ bs, int nb) {
    __shared__ int warp_sums[4];
    int t = threadIdx.x;
    int v = (t < nb) ? bs[t] : 0;
    int lane = t & 63, w = t >> 6;
    int x = v;
    for (int off = 1; off < 64; off <<= 1) {
        int y = __shfl_up(x, off);
        if (lane >= off) x += y;
    }
    if (lane == 63) warp_sums[w] = x;
    __syncthreads();
    int wo = 0;
    for (int i = 0; i < w; ++i) wo += warp_sums[i];
    if (t < nb) bs[t] = wo + x - v;
}

__global__ void scan3_kernel(int* __restrict__ row_start, const int* __restrict__ bs, int n) {
    int i = blockIdx.x * 256 + threadIdx.x;
    if (i < n) row_start[i] += bs[i >> 10];
}

__global__ void fill_kernel(const int* __restrict__ ei, const int* __restrict__ row_start,
                            int* __restrict__ cursor, int* __restrict__ csr_src, int E) {
    int i = blockIdx.x * 256 + threadIdx.x;
    if (i >= E) return;
    int src = ei[i];
    int dst = ei[E + i];
    int pos = row_start[dst] + atomicAdd(&cursor[dst], 1);
    csr_src[pos] = src;
}

// ---------------- fused gather: softmax + weighted sum + bias + tanh ----------------
__global__ __launch_bounds__(256) void gather_kernel(const int* __restrict__ row_start,
                                                     const int* __restrict__ deg,
                                                     const int* __restrict__ csr_src,
                                                     const float* __restrict__ alpha_s,
                                                     const float* __restrict__ alpha_d,
                                                     const unsigned short* __restrict__ h_bf,
                                                     const float* __restrict__ bias,
                                                     float* __restrict__ out, int n) {
    __shared__ float pbuf[4][CAP * 4];   // 16 KB
    int lane = threadIdx.x & 63;
    int wid  = threadIdx.x >> 6;
    int v = blockIdx.x * 4 + wid;
    if (v >= n) return;
    int start = row_start[v];
    int cnt = deg[v];
    float* wp = pbuf[wid];

    float4 ad  = *reinterpret_cast<const float4*>(alpha_d + (size_t)v * 4);
    float4 asv = *reinterpret_cast<const float4*>(alpha_s + (size_t)v * 4);

    float s0 = 0.f, s1 = 0.f, s2 = 0.f, s3 = 0.f;
    for (int j = lane; j < cnt; j += 64) {
        int src = csr_src[start + j];
        float4 as = *reinterpret_cast<const float4*>(alpha_s + (size_t)src * 4);
        float e0 = as.x + ad.x, e1 = as.y + ad.y, e2 = as.z + ad.z, e3 = as.w + ad.w;
        e0 = e0 > 0.f ? e0 : NEG * e0;
        e1 = e1 > 0.f ? e1 : NEG * e1;
        e2 = e2 > 0.f ? e2 : NEG * e2;
        e3 = e3 > 0.f ? e3 : NEG * e3;
        float p0 = __expf(e0), p1 = __expf(e1), p2 = __expf(e2), p3 = __expf(e3);
        if (j < CAP) *reinterpret_cast<float4*>(&wp[j * 4]) = make_float4(p0, p1, p2, p3);
        s0 += p0; s1 += p1; s2 += p2; s3 += p3;
    }
#pragma unroll
    for (int off = 32; off > 0; off >>= 1) {
        s0 += __shfl_xor(s0, off);
        s1 += __shfl_xor(s1, off);
        s2 += __shfl_xor(s2, off);
        s3 += __shfl_xor(s3, off);
    }
    float se0 = asv.x + ad.x, se1 = asv.y + ad.y, se2 = asv.z + ad.z, se3 = asv.w + ad.w;
    se0 = se0 > 0.f ? se0 : NEG * se0;
    se1 = se1 > 0.f ? se1 : NEG * se1;
    se2 = se2 > 0.f ? se2 : NEG * se2;
    se3 = se3 > 0.f ? se3 : NEG * se3;
    float ps0 = __expf(se0), ps1 = __expf(se1), ps2 = __expf(se2), ps3 = __expf(se3);
    s0 += ps0; s1 += ps1; s2 += ps2; s3 += ps3;

    float i0 = 1.f / (s0 + 1e-16f), i1 = 1.f / (s1 + 1e-16f);
    float i2 = 1.f / (s2 + 1e-16f), i3 = 1.f / (s3 + 1e-16f);

    float invH   = (lane < 32) ? ((lane < 16) ? i0 : i1) : ((lane < 48) ? i2 : i3);
    float adH    = (lane < 32) ? ((lane < 16) ? ad.x : ad.y) : ((lane < 48) ? ad.z : ad.w);
    float pselfH = (lane < 32) ? ((lane < 16) ? ps0 : ps1) : ((lane < 48) ? ps2 : ps3);
    int head = lane >> 4;

    float accx = 0.f, accy = 0.f;
    const unsigned* hb = reinterpret_cast<const unsigned*>(h_bf);
    int m = cnt < CAP ? cnt : CAP;
    int j = 0;
    for (; j + 4 <= m; j += 4) {
        int sA = csr_src[start + j];
        int sB = csr_src[start + j + 1];
        int sC = csr_src[start + j + 2];
        int sD = csr_src[start + j + 3];
        float wA = wp[(j + 0) * 4 + head] * invH;
        float wB = wp[(j + 1) * 4 + head] * invH;
        float wC = wp[(j + 2) * 4 + head] * invH;
        float wD = wp[(j + 3) * 4 + head] * invH;
        unsigned hA = hb[(size_t)sA * 64 + lane];
        unsigned hB = hb[(size_t)sB * 64 + lane];
        unsigned hC = hb[(size_t)sC * 64 + lane];
        unsigned hD = hb[(size_t)sD * 64 + lane];
        accx = fmaf(wA, bf16_to_f32((unsigned short)(hA & 0xffffu)), accx);
        accy = fmaf(wA, bf16_to_f32((unsigned short)(hA >> 16)),     accy);
        accx = fmaf(wB, bf16_to_f32((unsigned short)(hB & 0xffffu)), accx);
        accy = fmaf(wB, bf16_to_f32((unsigned short)(hB >> 16)),     accy);
        accx = fmaf(wC, bf16_to_f32((unsigned short)(hC & 0xffffu)), accx);
        accy = fmaf(wC, bf16_to_f32((unsigned short)(hC >> 16)),     accy);
        accx = fmaf(wD, bf16_to_f32((unsigned short)(hD & 0xffffu)), accx);
        accy = fmaf(wD, bf16_to_f32((unsigned short)(hD >> 16)),     accy);
    }
    for (; j < m; ++j) {
        int src = csr_src[start + j];
        float w = wp[j * 4 + head] * invH;
        unsigned hv = hb[(size_t)src * 64 + lane];
        accx = fmaf(w, bf16_to_f32((unsigned short)(hv & 0xffffu)), accx);
        accy = fmaf(w, bf16_to_f32((unsigned short)(hv >> 16)),     accy);
    }
    for (; j < cnt; ++j) {
        int src = csr_src[start + j];
        float as = alpha_s[(size_t)src * 4 + head];
        float e = as + adH;
        e = e > 0.f ? e : NEG * e;
        float w = __expf(e) * invH;
        unsigned hv = hb[(size_t)src * 64 + lane];
        accx = fmaf(w, bf16_to_f32((unsigned short)(hv & 0xffffu)), accx);
        accy = fmaf(w, bf16_to_f32((unsigned short)(hv >> 16)),     accy);
    }
    {
        float w = pselfH * invH;
        unsigned hv = hb[(size_t)v * 64 + lane];
        accx = fmaf(w, bf16_to_f32((unsigned short)(hv & 0xffffu)), accx);
        accy = fmaf(w, bf16_to_f32((unsigned short)(hv >> 16)),     accy);
    }
    float2 b = reinterpret_cast<const float2*>(bias)[lane];
    float2 o;
    o.x = tanhf(accx + b.x);
    o.y = tanhf(accy + b.y);
    reinterpret_cast<float2*>(out)[(size_t)v * 64 + lane] = o;
}

extern "C" void kernel_launch(void* const* d_in, const int* in_sizes, int n_in,
                              void* d_out, int out_size, void* d_ws, size_t ws_size,
                              hipStream_t stream) {
    const float* x     = (const float*)d_in[0];
    const float* W     = (const float*)d_in[1];
    const float* a_src = (const float*)d_in[2];
    const float* a_dst = (const float*)d_in[3];
    const float* bias  = (const float*)d_in[4];
    const int*   ei    = (const int*)d_in[5];

    const int n = in_sizes[0] / IN_DIM;        // 100000
    const int E = in_sizes[5] / 2;             // 1000000

    float* ws = (float*)d_ws;
    size_t off = 0;
    unsigned short* h_bf = (unsigned short*)(ws + off); off += (size_t)n * HC / 2;
    float* alpha_s = ws + off; off += (size_t)n * NHEAD;
    float* alpha_d = ws + off; off += (size_t)n * NHEAD;
    unsigned short* w_hi = (unsigned short*)(ws + off); off += 16384;   // 32768 ushorts
    int* ibase     = (int*)(ws + off);
    int* deg       = ibase;                    // n
    int* cursor    = ibase + n;                // n
    int* row_start = ibase + 2 * (size_t)n;    // n
    int* blk_sums  = ibase + 3 * (size_t)n;    // <=256
    int* csr_src   = ibase + 3 * (size_t)n + 256;  // E

    float* out = (float*)d_out;

    const int nb = (n + 1023) / 1024;

    hipMemsetAsync(deg, 0, 2 * (size_t)n * sizeof(int), stream);  // deg + cursor

    pack_w_kernel<<<16, 256, 0, stream>>>(W, w_hi);
    gemm_mfma_kernel<<<(n + 63) / 64, 512, 0, stream>>>(x, w_hi, a_src, a_dst,
                                                        h_bf, alpha_s, alpha_d, n);

    count_deg_kernel<<<(E + 255) / 256, 256, 0, stream>>>(ei, deg, E);
    scan1_kernel<<<nb, 256, 0, stream>>>(deg, row_start, blk_sums, n);
    scan2_kernel<<<1, 256, 0, stream>>>(blk_sums, nb);
    scan3_kernel<<<(n + 255) / 256, 256, 0, stream>>>(row_start, blk_sums, n);
    fill_kernel<<<(E + 255) / 256, 256, 0, stream>>>(ei, row_start, cursor, csr_src, E);

    gather_kernel<<<(n + 3) / 4, 256, 0, stream>>>(row_start, deg, csr_src,
                                                   alpha_s, alpha_d, h_bf, bias, out, n);
}

// Round 7
// 159.561 us; speedup vs baseline: 5.7291x; 1.5174x over previous
//
#include <hip/hip_runtime.h>

#define IN_DIM 256
#define HC     128   // H*C
#define NHEAD  4
#define NEG    0.2f
#define CAP    256   // per-wave LDS edge capacity (gather)
#define AS     264   // LDS row stride (ushorts) for staged A tiles
#define BKT    1024  // dsts per bucket
#define NBMAX  128   // max buckets (n <= 131072)
#define EPT    16    // edges per thread (bucket hist/scatter)
#define BE     4096  // edges per block = 256*EPT

typedef __attribute__((ext_vector_type(8))) short short8v;
typedef __attribute__((ext_vector_type(4))) float f32x4;
typedef __attribute__((ext_vector_type(4))) unsigned short ushort4v;

__device__ __forceinline__ unsigned short bf16_rn(float f) {
    unsigned u = __builtin_bit_cast(unsigned, f);
    return (unsigned short)((u + 0x7fffu + ((u >> 16) & 1u)) >> 16);
}
__device__ __forceinline__ float bf16_to_f32(unsigned short b) {
    unsigned u = ((unsigned)b) << 16;
    return __builtin_bit_cast(float, u);
}

// ---------------- pack W (hi bf16) into MFMA fragment order ----------------
__global__ void pack_w_kernel(const float* __restrict__ W,
                              unsigned short* __restrict__ w_hi) {
    int t = blockIdx.x * 256 + threadIdx.x;
    if (t >= 8 * 8 * 64) return;
    int l  = t & 63;
    int ct = (t >> 6) & 7;
    int s  = t >> 9;
    int kbase = s * 32 + (l >> 4) * 8;
    int col   = ct * 16 + (l & 15);
    size_t base = (size_t)t * 8;
#pragma unroll
    for (int e = 0; e < 8; ++e)
        w_hi[base + e] = bf16_rn(W[(size_t)(kbase + e) * HC + col]);
}

// ---------------- GEMM: h = x @ W via bf16 MFMA, x staged hi/lo in LDS ----------------
__global__ __launch_bounds__(512) void gemm_mfma_kernel(const float* __restrict__ x,
                                                        const unsigned short* __restrict__ w_hi,
                                                        const float* __restrict__ a_src,
                                                        const float* __restrict__ a_dst,
                                                        unsigned short* __restrict__ h_bf,
                                                        float* __restrict__ alpha_s,
                                                        float* __restrict__ alpha_d, int n) {
    __shared__ unsigned short s_hi[64][AS];
    __shared__ unsigned short s_lo[64][AS];
    __shared__ float pS[64][4];
    __shared__ float pD[64][4];

    const int tid = threadIdx.x;
    const int l   = tid & 63;
    const int wv  = tid >> 6;
    const int row0 = blockIdx.x * 64;

    const float4* x4 = reinterpret_cast<const float4*>(x);
#pragma unroll
    for (int i = 0; i < 8; ++i) {
        int f = tid + i * 512;
        int row = f >> 6, c4 = f & 63;
        float4 v = make_float4(0.f, 0.f, 0.f, 0.f);
        if (row0 + row < n) v = x4[(size_t)(row0 + row) * 64 + c4];
        float e[4] = {v.x, v.y, v.z, v.w};
        ushort4v hi, lo;
#pragma unroll
        for (int q = 0; q < 4; ++q) {
            unsigned short h16 = bf16_rn(e[q]);
            hi[q] = h16;
            lo[q] = bf16_rn(e[q] - bf16_to_f32(h16));
        }
        *reinterpret_cast<ushort4v*>(&s_hi[row][c4 * 4]) = hi;
        *reinterpret_cast<ushort4v*>(&s_lo[row][c4 * 4]) = lo;
    }
    __syncthreads();

    const int ct_g = wv & 3;
    const int rt_g = wv >> 2;
    const int rrow = l & 15;
    const int koff = (l >> 4) * 8;

    f32x4 acc[2][2];
#pragma unroll
    for (int a = 0; a < 2; ++a)
#pragma unroll
        for (int b = 0; b < 2; ++b) acc[a][b] = (f32x4){0.f, 0.f, 0.f, 0.f};

    for (int s = 0; s < 8; ++s) {
        short8v bh[2];
#pragma unroll
        for (int c = 0; c < 2; ++c) {
            int ct = ct_g * 2 + c;
            bh[c] = *reinterpret_cast<const short8v*>(w_hi + ((size_t)(s * 8 + ct) * 64 + l) * 8);
        }
#pragma unroll
        for (int r = 0; r < 2; ++r) {
            int arow = rt_g * 32 + r * 16 + rrow;
            short8v ah = *reinterpret_cast<const short8v*>(&s_hi[arow][koff + s * 32]);
            short8v al = *reinterpret_cast<const short8v*>(&s_lo[arow][koff + s * 32]);
#pragma unroll
            for (int c = 0; c < 2; ++c) {
                acc[r][c] = __builtin_amdgcn_mfma_f32_16x16x32_bf16(ah, bh[c], acc[r][c], 0, 0, 0);
                acc[r][c] = __builtin_amdgcn_mfma_f32_16x16x32_bf16(al, bh[c], acc[r][c], 0, 0, 0);
            }
        }
    }

#pragma unroll
    for (int r = 0; r < 2; ++r) {
#pragma unroll
        for (int c = 0; c < 2; ++c) {
            int col = (ct_g * 2 + c) * 16 + (l & 15);
#pragma unroll
            for (int q = 0; q < 4; ++q) {
                int row = row0 + rt_g * 32 + r * 16 + (l >> 4) * 4 + q;
                if (row < n) h_bf[(size_t)row * HC + col] = bf16_rn(acc[r][c][q]);
            }
        }
    }

    float asc[2], adc[2];
#pragma unroll
    for (int c = 0; c < 2; ++c) {
        int col = (ct_g * 2 + c) * 16 + (l & 15);
        asc[c] = a_src[col];
        adc[c] = a_dst[col];
    }
#pragma unroll
    for (int r = 0; r < 2; ++r) {
#pragma unroll
        for (int q = 0; q < 4; ++q) {
            float vS = acc[r][0][q] * asc[0] + acc[r][1][q] * asc[1];
            float vD = acc[r][0][q] * adc[0] + acc[r][1][q] * adc[1];
#pragma unroll
            for (int m = 1; m < 16; m <<= 1) {
                vS += __shfl_xor(vS, m);
                vD += __shfl_xor(vD, m);
            }
            if ((l & 15) == 0) {
                int rl = rt_g * 32 + r * 16 + (l >> 4) * 4 + q;
                pS[rl][ct_g] = vS;
                pD[rl][ct_g] = vD;
            }
        }
    }
    __syncthreads();
    if (tid < 256) {
        int rl = tid >> 2, h = tid & 3;
        int row = row0 + rl;
        if (row < n) {
            alpha_s[(size_t)row * 4 + h] = pS[rl][h];
            alpha_d[(size_t)row * 4 + h] = pD[rl][h];
        }
    }
}

// ---------------- CSR build: two-level counting sort by dst ----------------
// A1: bucket histogram (LDS-privatized)
__global__ __launch_bounds__(256) void bucket_hist_kernel(const int* __restrict__ ei,
                                                          int* __restrict__ bucket_cnt,
                                                          int E, int nb) {
    __shared__ int lh[NBMAX];
    int tid = threadIdx.x;
    if (tid < NBMAX) lh[tid] = 0;
    __syncthreads();
    int base = blockIdx.x * BE;
#pragma unroll
    for (int i = 0; i < EPT; ++i) {
        int e = base + i * 256 + tid;
        if (e < E) atomicAdd(&lh[ei[E + e] >> 10], 1);
    }
    __syncthreads();
    if (tid < nb && lh[tid]) atomicAdd(&bucket_cnt[tid], lh[tid]);
}

// A2: exclusive scan of bucket counts (nb <= 128); init cursor
__global__ __launch_bounds__(128) void bucket_scan_kernel(const int* __restrict__ bucket_cnt,
                                                          int* __restrict__ bucket_base,
                                                          int* __restrict__ bucket_cursor,
                                                          int nb) {
    __shared__ int ws0[1];
    int t = threadIdx.x;
    int v = (t < nb) ? bucket_cnt[t] : 0;
    int lane = t & 63, wd = t >> 6;
    int x = v;
#pragma unroll
    for (int off = 1; off < 64; off <<= 1) {
        int y = __shfl_up(x, off);
        if (lane >= off) x += y;
    }
    if (wd == 0 && lane == 63) ws0[0] = x;
    __syncthreads();
    int wo = wd ? ws0[0] : 0;
    int excl = wo + x - v;
    if (t < nb) { bucket_base[t] = excl; bucket_cursor[t] = excl; }
    if (t == 127) bucket_base[nb] = wo + x;   // total = E
}

// A3: scatter edges to bucket regions, block-grouped for coalescing
__global__ __launch_bounds__(256) void bucket_scatter_kernel(const int* __restrict__ ei,
                                                             int* __restrict__ bucket_cursor,
                                                             unsigned* __restrict__ bucket_data,
                                                             int E, int nb) {
    __shared__ int lh[NBMAX];
    __shared__ int lofs[NBMAX];
    __shared__ int gofs[NBMAX];
    __shared__ int ws0[1];
    __shared__ unsigned buf[BE];

    int tid = threadIdx.x;
    if (tid < NBMAX) lh[tid] = 0;
    __syncthreads();

    int base = blockIdx.x * BE;
    int bb[EPT]; unsigned wv[EPT]; int rr[EPT];
#pragma unroll
    for (int i = 0; i < EPT; ++i) {
        int e = base + i * 256 + tid;
        if (e < E) {
            int src = ei[e];
            int dst = ei[E + e];
            bb[i] = dst >> 10;
            wv[i] = (unsigned)src | ((unsigned)(dst & 1023) << 17);
            rr[i] = atomicAdd(&lh[bb[i]], 1);
        } else bb[i] = -1;
    }
    __syncthreads();

    // scan lh -> lofs (128 wide, 2 waves)
    int v_ = 0, x_ = 0;
    int lane = tid & 63, wd = tid >> 6;
    if (tid < NBMAX) {
        v_ = lh[tid]; x_ = v_;
#pragma unroll
        for (int off = 1; off < 64; off <<= 1) {
            int y = __shfl_up(x_, off);
            if (lane >= off) x_ += y;
        }
        if (wd == 0 && lane == 63) ws0[0] = x_;
    }
    __syncthreads();
    if (tid < NBMAX) {
        int wo = wd ? ws0[0] : 0;
        lofs[tid] = wo + x_ - v_;
    }
    __syncthreads();

#pragma unroll
    for (int i = 0; i < EPT; ++i)
        if (bb[i] >= 0) buf[lofs[bb[i]] + rr[i]] = wv[i];
    if (tid < nb) gofs[tid] = lh[tid] ? atomicAdd(&bucket_cursor[tid], lh[tid]) : 0;
    __syncthreads();

    // copy LDS-grouped chunks to global bucket regions (wave per bucket)
    int wid = tid >> 6;
    for (int bk = wid; bk < nb; bk += 4) {
        int lo = lofs[bk], cnt = lh[bk], g = gofs[bk];
        for (int j = lane; j < cnt; j += 64)
            bucket_data[g + j] = buf[lo + j];
    }
}

// B: per-bucket CSR finalize (LDS atomics only)
__global__ __launch_bounds__(1024) void bucket_build_kernel(const int* __restrict__ bucket_base,
                                                            const unsigned* __restrict__ bucket_data,
                                                            int* __restrict__ deg,
                                                            int* __restrict__ row_start,
                                                            int* __restrict__ csr_src, int n) {
    __shared__ int lc[BKT];
    __shared__ int sc[BKT];
    __shared__ int wsum[16];

    int b = blockIdx.x;
    int base = bucket_base[b];
    int end  = bucket_base[b + 1];
    int t = threadIdx.x;

    lc[t] = 0;
    __syncthreads();
    for (int i = base + t; i < end; i += 1024)
        atomicAdd(&lc[bucket_data[i] >> 17], 1);
    __syncthreads();

    int val = lc[t];
    int lane = t & 63, wd = t >> 6;
    int x = val;
#pragma unroll
    for (int off = 1; off < 64; off <<= 1) {
        int y = __shfl_up(x, off);
        if (lane >= off) x += y;
    }
    if (lane == 63) wsum[wd] = x;
    __syncthreads();
    if (wd == 0 && lane < 16) {
        int y = wsum[lane];
#pragma unroll
        for (int off = 1; off < 16; off <<= 1) {
            int z = __shfl_up(y, off);
            if (lane >= off) y += z;
        }
        wsum[lane] = y;
    }
    __syncthreads();
    int wo = wd ? wsum[wd - 1] : 0;
    int excl = wo + x - val;
    sc[t] = excl;
    int v = b * BKT + t;
    if (v < n) { deg[v] = val; row_start[v] = base + excl; }
    lc[t] = 0;   // reuse as cursor
    __syncthreads();

    for (int i = base + t; i < end; i += 1024) {
        unsigned w = bucket_data[i];
        int d = w >> 17;
        int src = (int)(w & 0x1FFFFu);
        int p = atomicAdd(&lc[d], 1);
        csr_src[base + sc[d] + p] = src;
    }
}

// ---------------- fused gather: softmax + weighted sum + bias + tanh ----------------
__global__ __launch_bounds__(256) void gather_kernel(const int* __restrict__ row_start,
                                                     const int* __restrict__ deg,
                                                     const int* __restrict__ csr_src,
                                                     const float* __restrict__ alpha_s,
                                                     const float* __restrict__ alpha_d,
                                                     const unsigned short* __restrict__ h_bf,
                                                     const float* __restrict__ bias,
                                                     float* __restrict__ out, int n) {
    __shared__ float pbuf[4][CAP * 4];   // 16 KB
    __shared__ int   sbuf[4][CAP];       // 4 KB
    int lane = threadIdx.x & 63;
    int wid  = threadIdx.x >> 6;
    int v = blockIdx.x * 4 + wid;
    if (v >= n) return;
    int start = row_start[v];
    int cnt = deg[v];
    float* wp = pbuf[wid];
    int* sp = sbuf[wid];

    float4 ad  = *reinterpret_cast<const float4*>(alpha_d + (size_t)v * 4);
    float4 asv = *reinterpret_cast<const float4*>(alpha_s + (size_t)v * 4);

    // pass 1: per-edge exp weights -> LDS; denominators
    float s0 = 0.f, s1 = 0.f, s2 = 0.f, s3 = 0.f;
    for (int j = lane; j < cnt; j += 64) {
        int src = csr_src[start + j];
        float4 as = *reinterpret_cast<const float4*>(alpha_s + (size_t)src * 4);
        float e0 = as.x + ad.x, e1 = as.y + ad.y, e2 = as.z + ad.z, e3 = as.w + ad.w;
        e0 = e0 > 0.f ? e0 : NEG * e0;
        e1 = e1 > 0.f ? e1 : NEG * e1;
        e2 = e2 > 0.f ? e2 : NEG * e2;
        e3 = e3 > 0.f ? e3 : NEG * e3;
        float p0 = __expf(e0), p1 = __expf(e1), p2 = __expf(e2), p3 = __expf(e3);
        if (j < CAP) {
            *reinterpret_cast<float4*>(&wp[j * 4]) = make_float4(p0, p1, p2, p3);
            sp[j] = src;
        }
        s0 += p0; s1 += p1; s2 += p2; s3 += p3;
    }
#pragma unroll
    for (int off = 32; off > 0; off >>= 1) {
        s0 += __shfl_xor(s0, off);
        s1 += __shfl_xor(s1, off);
        s2 += __shfl_xor(s2, off);
        s3 += __shfl_xor(s3, off);
    }
    float se0 = asv.x + ad.x, se1 = asv.y + ad.y, se2 = asv.z + ad.z, se3 = asv.w + ad.w;
    se0 = se0 > 0.f ? se0 : NEG * se0;
    se1 = se1 > 0.f ? se1 : NEG * se1;
    se2 = se2 > 0.f ? se2 : NEG * se2;
    se3 = se3 > 0.f ? se3 : NEG * se3;
    float ps0 = __expf(se0), ps1 = __expf(se1), ps2 = __expf(se2), ps3 = __expf(se3);
    s0 += ps0; s1 += ps1; s2 += ps2; s3 += ps3;

    float i0 = 1.f / (s0 + 1e-16f), i1 = 1.f / (s1 + 1e-16f);
    float i2 = 1.f / (s2 + 1e-16f), i3 = 1.f / (s3 + 1e-16f);

    float invH   = (lane < 32) ? ((lane < 16) ? i0 : i1) : ((lane < 48) ? i2 : i3);
    float adH    = (lane < 32) ? ((lane < 16) ? ad.x : ad.y) : ((lane < 48) ? ad.z : ad.w);
    float pselfH = (lane < 32) ? ((lane < 16) ? ps0 : ps1) : ((lane < 48) ? ps2 : ps3);
    int head = lane >> 4;

    // pass 2: unnormalized accumulate (normalize in epilogue), x4 unroll
    float accx = 0.f, accy = 0.f;
    const unsigned* hb = reinterpret_cast<const unsigned*>(h_bf);
    int m = cnt < CAP ? cnt : CAP;
    int j = 0;
    for (; j + 4 <= m; j += 4) {
        int sA = sp[j], sB = sp[j + 1], sC = sp[j + 2], sD = sp[j + 3];
        float wA = wp[(j + 0) * 4 + head];
        float wB = wp[(j + 1) * 4 + head];
        float wC = wp[(j + 2) * 4 + head];
        float wD = wp[(j + 3) * 4 + head];
        unsigned hA = hb[((unsigned)sA << 6) + lane];
        unsigned hB = hb[((unsigned)sB << 6) + lane];
        unsigned hC = hb[((unsigned)sC << 6) + lane];
        unsigned hD = hb[((unsigned)sD << 6) + lane];
        accx = fmaf(wA, bf16_to_f32((unsigned short)(hA & 0xffffu)), accx);
        accy = fmaf(wA, bf16_to_f32((unsigned short)(hA >> 16)),     accy);
        accx = fmaf(wB, bf16_to_f32((unsigned short)(hB & 0xffffu)), accx);
        accy = fmaf(wB, bf16_to_f32((unsigned short)(hB >> 16)),     accy);
        accx = fmaf(wC, bf16_to_f32((unsigned short)(hC & 0xffffu)), accx);
        accy = fmaf(wC, bf16_to_f32((unsigned short)(hC >> 16)),     accy);
        accx = fmaf(wD, bf16_to_f32((unsigned short)(hD & 0xffffu)), accx);
        accy = fmaf(wD, bf16_to_f32((unsigned short)(hD >> 16)),     accy);
    }
    for (; j < m; ++j) {
        int src = sp[j];
        float w = wp[j * 4 + head];
        unsigned hv = hb[((unsigned)src << 6) + lane];
        accx = fmaf(w, bf16_to_f32((unsigned short)(hv & 0xffffu)), accx);
        accy = fmaf(w, bf16_to_f32((unsigned short)(hv >> 16)),     accy);
    }
    for (; j < cnt; ++j) {   // overflow fallback: recompute weight
        int src = csr_src[start + j];
        float as = alpha_s[(size_t)src * 4 + head];
        float e = as + adH;
        e = e > 0.f ? e : NEG * e;
        float w = __expf(e);
        unsigned hv = hb[((unsigned)src << 6) + lane];
        accx = fmaf(w, bf16_to_f32((unsigned short)(hv & 0xffffu)), accx);
        accy = fmaf(w, bf16_to_f32((unsigned short)(hv >> 16)),     accy);
    }
    {
        unsigned hv = hb[((unsigned)v << 6) + lane];
        accx = fmaf(pselfH, bf16_to_f32((unsigned short)(hv & 0xffffu)), accx);
        accy = fmaf(pselfH, bf16_to_f32((unsigned short)(hv >> 16)),     accy);
    }
    float2 b = reinterpret_cast<const float2*>(bias)[lane];
    float2 o;
    o.x = tanhf(fmaf(accx, invH, b.x));
    o.y = tanhf(fmaf(accy, invH, b.y));
    reinterpret_cast<float2*>(out)[(size_t)v * 64 + lane] = o;
}

extern "C" void kernel_launch(void* const* d_in, const int* in_sizes, int n_in,
                              void* d_out, int out_size, void* d_ws, size_t ws_size,
                              hipStream_t stream) {
    const float* x     = (const float*)d_in[0];
    const float* W     = (const float*)d_in[1];
    const float* a_src = (const float*)d_in[2];
    const float* a_dst = (const float*)d_in[3];
    const float* bias  = (const float*)d_in[4];
    const int*   ei    = (const int*)d_in[5];

    const int n = in_sizes[0] / IN_DIM;        // 100000
    const int E = in_sizes[5] / 2;             // 1000000
    const int nb = (n + BKT - 1) / BKT;        // 98

    float* ws = (float*)d_ws;
    size_t off = 0;
    unsigned short* h_bf = (unsigned short*)(ws + off); off += (size_t)n * HC / 2;
    float* alpha_s = ws + off; off += (size_t)n * NHEAD;
    float* alpha_d = ws + off; off += (size_t)n * NHEAD;
    unsigned short* w_hi = (unsigned short*)(ws + off); off += 16384;
    int* ibase        = (int*)(ws + off);
    int* deg          = ibase;                        // n
    int* row_start    = ibase + n;                    // n
    int* bucket_cnt   = ibase + 2 * (size_t)n;        // NBMAX
    int* bucket_base  = bucket_cnt + NBMAX;           // NBMAX+1
    int* bucket_cursor= bucket_base + NBMAX + 1;      // NBMAX
    unsigned* bucket_data = (unsigned*)(bucket_cursor + NBMAX);  // E
    int* csr_src      = (int*)(bucket_data + E);      // E

    float* out = (float*)d_out;

    const int nblkE = (E + BE - 1) / BE;

    hipMemsetAsync(bucket_cnt, 0, NBMAX * sizeof(int), stream);

    pack_w_kernel<<<16, 256, 0, stream>>>(W, w_hi);
    gemm_mfma_kernel<<<(n + 63) / 64, 512, 0, stream>>>(x, w_hi, a_src, a_dst,
                                                        h_bf, alpha_s, alpha_d, n);

    bucket_hist_kernel<<<nblkE, 256, 0, stream>>>(ei, bucket_cnt, E, nb);
    bucket_scan_kernel<<<1, 128, 0, stream>>>(bucket_cnt, bucket_base, bucket_cursor, nb);
    bucket_scatter_kernel<<<nblkE, 256, 0, stream>>>(ei, bucket_cursor, bucket_data, E, nb);
    bucket_build_kernel<<<nb, 1024, 0, stream>>>(bucket_base, bucket_data,
                                                 deg, row_start, csr_src, n);

    gather_kernel<<<(n + 3) / 4, 256, 0, stream>>>(row_start, deg, csr_src,
                                                   alpha_s, alpha_d, h_bf, bias, out, n);
}